// Round 3
// baseline (305.646 us; speedup 1.0000x reference)
//
#include <hip/hip_runtime.h>
#include <math.h>

#define HID 256
#define EPS_REG 1e-6

typedef __attribute__((ext_vector_type(8))) short short8;
typedef __attribute__((ext_vector_type(4))) short short4v;
typedef __attribute__((ext_vector_type(4))) float v4f;

#define MFMA_BF16(a, b, c) __builtin_amdgcn_mfma_f32_16x16x32_bf16((a), (b), (c), 0, 0, 0)

// ---------------------------------------------------------------------------
// Fast tanh: tanh(z) = 1 - 2/(exp(2z)+1). ~6 instr, <=2 ulp.
// ---------------------------------------------------------------------------
__device__ __forceinline__ float fast_tanh(float z) {
    const float e = __expf(2.0f * z);
    const float d = e + 1.0f;
    float r = __builtin_amdgcn_rcpf(d);
    r = r * (2.0f - d * r);              // Newton refine to full fp32
    return fmaf(-2.0f, r, 1.0f);
}

// ---------------------------------------------------------------------------
// Cheap RTN bf16 3-way split: v ~= hi + mid + lo (round-half-up, 2 ops/stage).
// ---------------------------------------------------------------------------
__device__ __forceinline__ float rtn_bf16(float v, short* s) {
    unsigned r = (__float_as_uint(v) + 0x8000u) & 0xFFFF0000u;
    *s = (short)(r >> 16);
    return __uint_as_float(r);
}
__device__ __forceinline__ void split3(float v, short* a, short* b, short* c) {
    float f0 = rtn_bf16(v, a);
    float r1 = v - f0;
    float f1 = rtn_bf16(r1, b);
    float r2 = r1 - f1;
    (void)rtn_bf16(r2, c);
}

// ---------------------------------------------------------------------------
// Prep: split W1 into bf16 hi/mid/lo laid out as per-lane MFMA A-fragments
// for phase 1 (A = W1 rows) and phase 2 (A = W1 columns). 6 x 128KB = 768KB.
// ---------------------------------------------------------------------------
__global__ void prep_w1_frags(const float* __restrict__ W1, short* __restrict__ ws) {
    const int gid   = blockIdx.x * 128 + threadIdx.x;   // 0..16383
    const int lane  = gid & 63;
    const int ks    = (gid >> 6) & 7;
    const int rt    = (gid >> 9) & 15;
    const int which = gid >> 13;                        // 0: A1, 1: A2
    const int m = lane & 15, q = lane >> 4;

    float v[8];
    if (which == 0) {
        const float* p = W1 + (size_t)(rt*16 + m)*HID + ks*32 + q*8;
        const float4 va = *(const float4*)(p);
        const float4 vb = *(const float4*)(p + 4);
        v[0]=va.x; v[1]=va.y; v[2]=va.z; v[3]=va.w;
        v[4]=vb.x; v[5]=vb.y; v[6]=vb.z; v[7]=vb.w;
    } else {
        const float* p = W1 + (size_t)(ks*32 + q*8)*HID + rt*16 + m;
#pragma unroll
        for (int t = 0; t < 8; ++t) v[t] = p[(size_t)t*HID];
    }
    short8 h8, m8, l8;
#pragma unroll
    for (int t = 0; t < 8; ++t) {
        short sh, sm, sl;
        split3(v[t], &sh, &sm, &sl);
        h8[t] = sh; m8[t] = sm; l8[t] = sl;
    }
    const size_t base = (size_t)which*3*65536 + ((size_t)(rt*8 + ks)*64 + lane)*8;
    *(short8*)(ws + base)          = h8;
    *(short8*)(ws + base + 65536)  = m8;
    *(short8*)(ws + base + 131072) = l8;
}

// ---------------------------------------------------------------------------
// R16: wave-group pipeline.
// R14/R15 post-mortem: hipcc will NOT interleave MFMA and VALU within one
// instruction stream (fn-level fusion: 294us; ks-granular: 261us; both with
// MfmaUtil+VALUBusy ~= 70% < R13's 85%). But m114 (guide): MFMA-wave and
// VALU-wave on the SAME CU co-run at time ~= max. So: 1024 thr = 16 waves =
// two 8-wave groups, each running the unmodified R13 phase chain on its own
// samples/buffers, staggered by one phase. Each SIMD hosts 2 A-waves + 2
// B-waves -> matrix and vector pipes are fed concurrently by DIFFERENT waves.
// Numerics bit-identical to R13 per group.
// ---------------------------------------------------------------------------
#define FRAG_NT_STRIDE 13056   // 3 bufs * 32 groups * 136 shorts
#define FRAG_BUF_STRIDE 4352   // 32 groups * 136
#define BFRAG_SHORTS 26112     // 2 nt * 13056
#define M0H_FLOATS 2304        // 256 * 9
#define PIPE_LDS_BYTES 122880  // 2*52224 + 2*9216

// ---- Phase 0: layer-0 forward + tangents --> M0 + B1 frags ----------------
__device__ __forceinline__ void lnn_phase0(const float* __restrict__ x,
    const float* __restrict__ W0, const float* __restrict__ b0,
    int samp_base, short* __restrict__ Bf, float* __restrict__ M0, int tid)
{
    const int j  = tid & 255;
    const int s0 = (tid >> 8) * 4;
    float w0r[7];
#pragma unroll
    for (int d = 0; d < 7; ++d) w0r[d] = W0[j*7 + d];
    const float bj = b0[j];
    const int kbase = (j >> 3)*136 + (j & 7);    // G*136 + t
#pragma unroll
    for (int si = 0; si < 4; ++si) {
        const int s = s0 + si;
        const float* xs = x + (size_t)(samp_base + s)*7;
        float z = bj;
#pragma unroll
        for (int d = 0; d < 7; ++d) z = fmaf(w0r[d], xs[d], z);
        const float h  = fast_tanh(z);
        const float sg = 1.0f - h*h;
        M0[j*9 + s] = h;
        const int nt = s >> 2;
        const int cb = (s & 3) * 4;              // col base within tile
        float vals[4] = {h, sg*w0r[4], sg*w0r[5], sg*w0r[6]};
#pragma unroll
        for (int comp = 0; comp < 4; ++comp) {
            short sh, sm, sl;
            split3(vals[comp], &sh, &sm, &sl);
            const int a = nt*FRAG_NT_STRIDE + kbase + (cb + comp)*8;
            Bf[a]                     = sh;
            Bf[a + FRAG_BUF_STRIDE]   = sm;
            Bf[a + 2*FRAG_BUF_STRIDE] = sl;
        }
    }
}

// ---- MFMA k-loop: acc += A x B (bf16x3, 6-product fp32 emulation) ---------
__device__ __forceinline__ void lnn_mm(const short8* __restrict__ Ah,
    const short8* __restrict__ Am, const short8* __restrict__ Al,
    const short* __restrict__ Bf, int w, int lane, int boff, v4f acc[2][2])
{
    short8 pah[2][2], pam[2][2], pal[2][2];   // [parity][rtl] A prefetch
#pragma unroll
    for (int rtl = 0; rtl < 2; ++rtl) {
        const size_t fi = ((size_t)((w*2 + rtl)*8))*64 + lane;
        pah[0][rtl] = Ah[fi]; pam[0][rtl] = Am[fi]; pal[0][rtl] = Al[fi];
    }
#pragma unroll
    for (int ks = 0; ks < 8; ++ks) {
        const int cur = ks & 1, nxt = cur ^ 1;
        if (ks < 7) {
#pragma unroll
            for (int rtl = 0; rtl < 2; ++rtl) {
                const size_t fi = ((size_t)((w*2 + rtl)*8 + ks + 1))*64 + lane;
                pah[nxt][rtl] = Ah[fi]; pam[nxt][rtl] = Am[fi]; pal[nxt][rtl] = Al[fi];
            }
        }
        short8 bh[2], bm[2], bl[2];
#pragma unroll
        for (int nt = 0; nt < 2; ++nt) {
            const int a = nt*FRAG_NT_STRIDE + ks*544 + boff;
            bh[nt] = *(const short8*)(&Bf[a]);
            bm[nt] = *(const short8*)(&Bf[a + FRAG_BUF_STRIDE]);
            bl[nt] = *(const short8*)(&Bf[a + 2*FRAG_BUF_STRIDE]);
        }
#pragma unroll
        for (int rtl = 0; rtl < 2; ++rtl) {
            const short8 ah = pah[cur][rtl];
            const short8 am = pam[cur][rtl];
            const short8 al = pal[cur][rtl];
#pragma unroll
            for (int nt = 0; nt < 2; ++nt) {
                acc[rtl][nt] = MFMA_BF16(ah, bl[nt], acc[rtl][nt]);
                acc[rtl][nt] = MFMA_BF16(al, bh[nt], acc[rtl][nt]);
                acc[rtl][nt] = MFMA_BF16(am, bm[nt], acc[rtl][nt]);
                acc[rtl][nt] = MFMA_BF16(am, bh[nt], acc[rtl][nt]);
                acc[rtl][nt] = MFMA_BF16(ah, bm[nt], acc[rtl][nt]);
                acc[rtl][nt] = MFMA_BF16(ah, bh[nt], acc[rtl][nt]);
            }
        }
    }
}

// ---- Epilogue 1: layer-2 nonlinearity + reverse seed --> B2 frags ---------
__device__ __forceinline__ void lnn_epi1(v4f acc[2][2], short* __restrict__ Bf,
    const float* __restrict__ b1, const float* __restrict__ W2,
    int w, int lane, int q, int c)
{
    const int myreg = c & 3;
#pragma unroll
    for (int rtl = 0; rtl < 2; ++rtl) {
        const int base = (w*2 + rtl)*16;
        float b1r[4], w2r[4];
#pragma unroll
        for (int r = 0; r < 4; ++r) {
            b1r[r] = b1[base + q*4 + r];
            w2r[r] = W2[base + q*4 + r];
        }
        const int G  = (base >> 3) + (q >> 1);
        const int tq = (q & 1) * 4;
#pragma unroll
        for (int nt = 0; nt < 2; ++nt) {
            short4v ph, pm, pl;
#pragma unroll
            for (int r = 0; r < 4; ++r) {
                const float z0 = __shfl(acc[rtl][nt][r] + b1r[r], lane & ~3, 64);
                const float h1 = fast_tanh(z0);
                const float s1 = 1.0f - h1*h1;
                const float av = acc[rtl][nt][r];
                const float u  = (myreg == 0) ? (w2r[r]*s1)
                                              : (-2.0f*w2r[r]*h1*s1)*av;
                short sh, sm, sl;
                split3(u, &sh, &sm, &sl);
                ph[r] = sh; pm[r] = sm; pl[r] = sl;
            }
            const int a = nt*FRAG_NT_STRIDE + G*136 + c*8 + tq;
            *(short4v*)(&Bf[a])                     = ph;
            *(short4v*)(&Bf[a + FRAG_BUF_STRIDE])   = pm;
            *(short4v*)(&Bf[a + 2*FRAG_BUF_STRIDE]) = pl;
        }
    }
}

// ---- Epilogue 2: back through layer-0 --> U0 plain (overlay Bf) -----------
__device__ __forceinline__ void lnn_epi2(v4f acc2[2][2], short* __restrict__ Bf,
    const float* __restrict__ M0, const float* __restrict__ W0,
    int w, int lane, int q, int c)
{
    float* U0 = (float*)Bf;      // [j][s*4+comp], stride 36
#pragma unroll
    for (int rtl = 0; rtl < 2; ++rtl) {
#pragma unroll
        for (int reg = 0; reg < 4; ++reg) {
            const int j = (w*2 + rtl)*16 + q*4 + reg;
            const float w0sel = W0[j*7 + 3 + (c & 3)];  // dummy read for comp 0
#pragma unroll
            for (int nt = 0; nt < 2; ++nt) {
                const int s = nt*4 + (c >> 2);
                const float pv = acc2[rtl][nt][reg];
                const float p0 = __shfl(pv, lane & ~3, 64);
                const float h0 = M0[j*9 + s];
                const float sg = 1.0f - h0*h0;
                const float t2 = -2.0f * p0 * h0 * sg;
                const float res = ((c & 3) == 0) ? (p0*sg)
                                                 : fmaf(pv, sg, t2 * w0sel);
                U0[j*36 + s*4 + (c & 3)] = res;
            }
        }
    }
}

// ---- Phase 3: project through W0^T, reduce, assemble, solve ---------------
__device__ __forceinline__ void lnn_phase3(const float* __restrict__ x,
    const float* __restrict__ W0, short* __restrict__ Bf,
    int samp_base, float* __restrict__ out, int w, int tid)
{
    const float* U0 = (const float*)Bf;
    float* scratch = ((float*)Bf) + 9216 + w * 425;   // [25][17]
    const int t = tid & 63;
    float part[25];
#pragma unroll
    for (int qq = 0; qq < 25; ++qq) part[qq] = 0.0f;

#pragma unroll
    for (int m = 0; m < 4; ++m) {
        const int j = t + 64*m;
        const float4 uv = *(const float4*)(&U0[j*36 + w*4]);
        float w0d[7];
#pragma unroll
        for (int d = 0; d < 7; ++d) w0d[d] = W0[j*7 + d];
#pragma unroll
        for (int d = 0; d < 4; ++d) part[d] = fmaf(uv.x, w0d[d], part[d]);
#pragma unroll
        for (int d = 0; d < 7; ++d) {
            part[4  + d] = fmaf(uv.y, w0d[d], part[4  + d]);
            part[11 + d] = fmaf(uv.z, w0d[d], part[11 + d]);
            part[18 + d] = fmaf(uv.w, w0d[d], part[18 + d]);
        }
    }
    // stages 1-2: quad-local sums
#pragma unroll
    for (int off = 1; off <= 2; off <<= 1)
#pragma unroll
        for (int qq = 0; qq < 25; ++qq)
            part[qq] += __shfl_xor(part[qq], off, 64);
    {
        const int quad = t >> 2;
        if ((t & 3) == 0) {
#pragma unroll
            for (int e = 0; e < 25; ++e)
                scratch[e*17 + quad] = part[e];
        }
    }
    if (t < 25) {
        float tot = 0.0f;
#pragma unroll
        for (int k = 0; k < 16; ++k) tot += scratch[t*17 + k];
        scratch[t*17 + 16] = tot;
    }

    if (t == 0) {
        double g[25];
#pragma unroll
        for (int e = 0; e < 25; ++e) g[e] = (double)scratch[e*17 + 16];

        const float* xs = x + (size_t)(samp_base + w)*7;
        const double x1 = xs[2], x2 = xs[3];
        const double dq0 = xs[4], dq1 = xs[5], dth = xs[6];

        double M[3][3], rhs[3];
#pragma unroll
        for (int i = 0; i < 3; ++i) {
            const double J0 = g[4 + i*7 + 0];
            const double J1 = g[4 + i*7 + 1];
            const double J2 = -x2*g[4 + i*7 + 2] + x1*g[4 + i*7 + 3];
            const double dL = (i == 0) ? g[0]
                            : (i == 1) ? g[1]
                            : (-x2*g[2] + x1*g[3]);
            M[i][0] = g[4 + i*7 + 4] + (i == 0 ? EPS_REG : 0.0);
            M[i][1] = g[4 + i*7 + 5] + (i == 1 ? EPS_REG : 0.0);
            M[i][2] = g[4 + i*7 + 6] + (i == 2 ? EPS_REG : 0.0);
            rhs[i]  = dL - (J0*dq0 + J1*dq1 + J2*dth);
        }
        // branch-free fp64 Cramer / adjugate solve
        const double c00 = M[1][1]*M[2][2] - M[1][2]*M[2][1];
        const double c01 = M[1][2]*M[2][0] - M[1][0]*M[2][2];
        const double c02 = M[1][0]*M[2][1] - M[1][1]*M[2][0];
        const double det = M[0][0]*c00 + M[0][1]*c01 + M[0][2]*c02;
        const double inv = 1.0 / det;
        const double c10 = M[0][2]*M[2][1] - M[0][1]*M[2][2];
        const double c11 = M[0][0]*M[2][2] - M[0][2]*M[2][0];
        const double c12 = M[0][1]*M[2][0] - M[0][0]*M[2][1];
        const double c20 = M[0][1]*M[1][2] - M[0][2]*M[1][1];
        const double c21 = M[0][2]*M[1][0] - M[0][0]*M[1][2];
        const double c22 = M[0][0]*M[1][1] - M[0][1]*M[1][0];
        const double sol0 = (c00*rhs[0] + c10*rhs[1] + c20*rhs[2]) * inv;
        const double sol1 = (c01*rhs[0] + c11*rhs[1] + c21*rhs[2]) * inv;
        const double sol2 = (c02*rhs[0] + c12*rhs[1] + c22*rhs[2]) * inv;

        float* o = out + (size_t)(samp_base + w)*7;
        o[0] = (float)dq0;
        o[1] = (float)dq1;
        o[2] = (float)(-x2*dth);
        o[3] = (float)( x1*dth);
        o[4] = (float)sol0;
        o[5] = (float)sol1;
        o[6] = (float)sol2;
    }
}

// ---------------------------------------------------------------------------
// Wave-group pipelined kernel: 1024 threads = waves 0-7 (group A) + 8-15
// (group B). Each group = the full R13 block on its own 8 samples and its
// own LDS half. Phases staggered by one region so MFMA regions of one group
// coincide with VALU regions of the other; each SIMD hosts 2 waves of each.
// __syncthreads() between regions provides both groups' internal barriers.
// ---------------------------------------------------------------------------
__global__ __launch_bounds__(1024, 4)
void lnn_pipe(const float* __restrict__ x,
              const float* __restrict__ W0, const float* __restrict__ b0,
              const float* __restrict__ b1, const float* __restrict__ W2,
              const short* __restrict__ ws,
              float* __restrict__ out)
{
    extern __shared__ __align__(16) short smem[];

    const int tid  = threadIdx.x;
    const int w16  = tid >> 6;           // 0..15
    const int isA  = (w16 < 8) ? 1 : 0;
    const int w    = w16 & 7;            // group-local wave 0..7
    const int lane = tid & 63;
    const int gtid = w*64 + lane;        // group-local tid 0..511

    short* Bf = smem + (isA ? 0 : BFRAG_SHORTS);
    float* M0 = (float*)(smem + 2*BFRAG_SHORTS) + (isA ? 0 : M0H_FLOATS);
    const int samp0 = blockIdx.x * 16 + (isA ? 0 : 8);

    const short8* A1h = (const short8*)ws;
    const short8* A1m = A1h + 8192;
    const short8* A1l = A1h + 16384;
    const short8* A2h = A1h + 24576;
    const short8* A2m = A1h + 32768;
    const short8* A2l = A1h + 40960;

    const int q = lane >> 4;
    const int c = lane & 15;
    const int boff = q*136 + c*8;

    // R0: A:P0 | B:idle
    if (isA) lnn_phase0(x, W0, b0, samp0, Bf, M0, gtid);
    __syncthreads();

    // R1: A:MM1 (MFMA) | B:P0 (VALU)
    v4f acc[2][2];
#pragma unroll
    for (int r = 0; r < 2; ++r)
#pragma unroll
        for (int n = 0; n < 2; ++n) acc[r][n] = (v4f){0.f, 0.f, 0.f, 0.f};
    if (isA) lnn_mm(A1h, A1m, A1l, Bf, w, lane, boff, acc);
    else     lnn_phase0(x, W0, b0, samp0, Bf, M0, gtid);
    __syncthreads();

    // R2: A:E1 (VALU) | B:MM1 (MFMA)
    if (isA) lnn_epi1(acc, Bf, b1, W2, w, lane, q, c);
    else     lnn_mm(A1h, A1m, A1l, Bf, w, lane, boff, acc);
    __syncthreads();

    // R3: A:MM2 (MFMA) | B:E1 (VALU)
    v4f acc2[2][2];
#pragma unroll
    for (int r = 0; r < 2; ++r)
#pragma unroll
        for (int n = 0; n < 2; ++n) acc2[r][n] = (v4f){0.f, 0.f, 0.f, 0.f};
    if (isA) lnn_mm(A2h, A2m, A2l, Bf, w, lane, boff, acc2);
    else     lnn_epi1(acc, Bf, b1, W2, w, lane, q, c);
    __syncthreads();

    // R4: A:E2 (VALU) | B:MM2 (MFMA)
    if (isA) lnn_epi2(acc2, Bf, M0, W0, w, lane, q, c);
    else     lnn_mm(A2h, A2m, A2l, Bf, w, lane, boff, acc2);
    __syncthreads();

    // R5: A:P3 | B:E2   (both VALU; disjoint buffers)
    if (isA) lnn_phase3(x, W0, Bf, samp0, out, w, gtid);
    else     lnn_epi2(acc2, Bf, M0, W0, w, lane, q, c);
    __syncthreads();

    // R6: B:P3
    if (!isA) lnn_phase3(x, W0, Bf, samp0, out, w, gtid);
}

// ===========================================================================
// R13 8-sample kernel, kept as fallback (if >64KB dynamic LDS is refused or
// B % 16 != 0). Measured 226 us, MfmaUtil 42 / VALUBusy 43.
// ===========================================================================
__global__ __launch_bounds__(512, 4)
void lnn_mfma(const float* __restrict__ x,
              const float* __restrict__ W0, const float* __restrict__ b0,
              const float* __restrict__ b1, const float* __restrict__ W2,
              const short* __restrict__ ws,
              float* __restrict__ out)
{
    __shared__ __align__(16) short Bfrag[26112];     // 52224 B
    __shared__ float M0h[HID * 9];                   // h0 per (j, s), stride 9

    const int tid   = threadIdx.x;
    const int samp0 = blockIdx.x * 8;
    const int lane  = tid & 63;
    const int w     = tid >> 6;                      // wave 0..7

    lnn_phase0(x, W0, b0, samp0, Bfrag, M0h, tid);
    __syncthreads();

    const short8* A1h = (const short8*)ws;
    const short8* A1m = A1h + 8192;
    const short8* A1l = A1h + 16384;
    const short8* A2h = A1h + 24576;
    const short8* A2m = A1h + 32768;
    const short8* A2l = A1h + 40960;

    const int q = lane >> 4;
    const int c = lane & 15;
    const int boff = q*136 + c*8;

    v4f acc[2][2];
#pragma unroll
    for (int r = 0; r < 2; ++r)
#pragma unroll
        for (int n = 0; n < 2; ++n) acc[r][n] = (v4f){0.f, 0.f, 0.f, 0.f};
    lnn_mm(A1h, A1m, A1l, Bfrag, w, lane, boff, acc);
    __syncthreads();

    lnn_epi1(acc, Bfrag, b1, W2, w, lane, q, c);
    __syncthreads();

    v4f acc2[2][2];
#pragma unroll
    for (int r = 0; r < 2; ++r)
#pragma unroll
        for (int n = 0; n < 2; ++n) acc2[r][n] = (v4f){0.f, 0.f, 0.f, 0.f};
    lnn_mm(A2h, A2m, A2l, Bfrag, w, lane, boff, acc2);
    __syncthreads();

    lnn_epi2(acc2, Bfrag, M0h, W0, w, lane, q, c);
    __syncthreads();

    lnn_phase3(x, W0, Bfrag, samp0, out, w, tid);
}

// ===========================================================================
// Deep fallback (proven round-3 kernel, fp32 VALU): used if ws too small.
// ===========================================================================
#define TS8 8
#define SCP 36

__global__ void transpose_w1(const float* __restrict__ W1, float* __restrict__ W1T) {
    __shared__ float tile[32][33];
    const int bx = blockIdx.x & 7;
    const int by = blockIdx.x >> 3;
    const int tx = threadIdx.x & 31;
    const int ty = threadIdx.x >> 5;
#pragma unroll
    for (int q = 0; q < 4; ++q)
        tile[ty + q*8][tx] = W1[(by*32 + ty + q*8)*HID + bx*32 + tx];
    __syncthreads();
#pragma unroll
    for (int q = 0; q < 4; ++q)
        W1T[(bx*32 + ty + q*8)*HID + by*32 + tx] = tile[tx][ty + q*8];
}

__global__ __launch_bounds__(256, 2)
void lnn_fused(const float* __restrict__ x,
               const float* __restrict__ W0, const float* __restrict__ b0,
               const float* __restrict__ W1, const float* __restrict__ b1,
               const float* __restrict__ W2,
               const float* __restrict__ W1T, const int useT,
               float* __restrict__ out)
{
    __shared__ float M0[HID * SCP];
    __shared__ float U [HID * SCP];
    const int tid   = threadIdx.x;
    const int samp0 = blockIdx.x * TS8;
    {
        const int j = tid;
        float w0r[7];
#pragma unroll
        for (int d = 0; d < 7; ++d) w0r[d] = W0[j*7 + d];
        const float bj = b0[j];
#pragma unroll
        for (int s = 0; s < TS8; ++s) {
            const float* xs = x + (size_t)(samp0 + s)*7;
            float z = bj;
#pragma unroll
            for (int d = 0; d < 7; ++d) z = fmaf(w0r[d], xs[d], z);
            const float h  = tanhf(z);
            const float sg = 1.0f - h*h;
            float4 v = {h, sg * w0r[4], sg * w0r[5], sg * w0r[6]};
            *(float4*)(&M0[j*SCP + s*4]) = v;
        }
    }
    __syncthreads();
    const int it = tid & 63;
    const int ct = tid >> 6;
    float acc[4][8];
#pragma unroll
    for (int r = 0; r < 4; ++r)
#pragma unroll
        for (int c = 0; c < 8; ++c) acc[r][c] = 0.0f;
    if (useT) {
#pragma unroll 4
        for (int j = 0; j < HID; ++j) {
            const float4 w4 = *(const float4*)(W1T + (size_t)j*HID + it*4);
            const float4 ma = *(const float4*)(&M0[j*SCP + ct*8]);
            const float4 mb = *(const float4*)(&M0[j*SCP + ct*8 + 4]);
            const float w[4] = {w4.x, w4.y, w4.z, w4.w};
            const float m[8] = {ma.x, ma.y, ma.z, ma.w, mb.x, mb.y, mb.z, mb.w};
#pragma unroll
            for (int r = 0; r < 4; ++r)
#pragma unroll
                for (int c = 0; c < 8; ++c)
                    acc[r][c] = fmaf(w[r], m[c], acc[r][c]);
        }
    } else {
#pragma unroll 2
        for (int j = 0; j < HID; ++j) {
            float w[4];
#pragma unroll
            for (int r = 0; r < 4; ++r) w[r] = W1[(size_t)(it*4 + r)*HID + j];
            const float4 ma = *(const float4*)(&M0[j*SCP + ct*8]);
            const float4 mb = *(const float4*)(&M0[j*SCP + ct*8 + 4]);
            const float m[8] = {ma.x, ma.y, ma.z, ma.w, mb.x, mb.y, mb.z, mb.w};
#pragma unroll
            for (int r = 0; r < 4; ++r)
#pragma unroll
                for (int c = 0; c < 8; ++c)
                    acc[r][c] = fmaf(w[r], m[c], acc[r][c]);
        }
    }
    {
#pragma unroll
        for (int r = 0; r < 4; ++r) {
            const int i = it*4 + r;
            const float b1i = b1[i];
            const float w2i = W2[i];
#pragma unroll
            for (int cs = 0; cs < 2; ++cs) {
                const float z1 = acc[r][cs*4+0] + b1i;
                const float h1 = tanhf(z1);
                const float s1 = 1.0f - h1*h1;
                float4 uv;
                uv.x = w2i * s1;
                const float m2 = -2.0f * w2i * h1 * s1;
                uv.y = m2 * acc[r][cs*4+1];
                uv.z = m2 * acc[r][cs*4+2];
                uv.w = m2 * acc[r][cs*4+3];
                *(float4*)(&U[i*SCP + ct*8 + cs*4]) = uv;
            }
        }
    }
    __syncthreads();
    float acc2[4][8];
#pragma unroll
    for (int r = 0; r < 4; ++r)
#pragma unroll
        for (int c = 0; c < 8; ++c) acc2[r][c] = 0.0f;
#pragma unroll 4
    for (int i = 0; i < HID; ++i) {
        const float4 w4 = *(const float4*)(W1 + (size_t)i*HID + it*4);
        const float4 ua = *(const float4*)(&U[i*SCP + ct*8]);
        const float4 ub = *(const float4*)(&U[i*SCP + ct*8 + 4]);
        const float w[4] = {w4.x, w4.y, w4.z, w4.w};
        const float m[8] = {ua.x, ua.y, ua.z, ua.w, ub.x, ub.y, ub.z, ub.w};
#pragma unroll
        for (int r = 0; r < 4; ++r)
#pragma unroll
            for (int c = 0; c < 8; ++c)
                acc2[r][c] = fmaf(w[r], m[c], acc2[r][c]);
    }
    __syncthreads();
    {
#pragma unroll
        for (int r = 0; r < 4; ++r) {
            const int j = it*4 + r;
#pragma unroll
            for (int cs = 0; cs < 2; ++cs) {
                const int scb = ct*8 + cs*4;
                const float4 mm = *(const float4*)(&M0[j*SCP + scb]);
                const float h0v = mm.x;
                const float sg  = 1.0f - h0v*h0v;
                const float p   = acc2[r][cs*4+0];
                const float t2  = -2.0f * p * h0v;
                float4 uv;
                uv.x = p * sg;
                uv.y = fmaf(acc2[r][cs*4+1], sg, t2 * mm.y);
                uv.z = fmaf(acc2[r][cs*4+2], sg, t2 * mm.z);
                uv.w = fmaf(acc2[r][cs*4+3], sg, t2 * mm.w);
                *(float4*)(&U[j*SCP + scb]) = uv;
            }
        }
    }
    __syncthreads();
    const int s = tid >> 5;
    const int t = tid & 31;
    float part[25];
#pragma unroll
    for (int qq = 0; qq < 25; ++qq) part[qq] = 0.0f;
#pragma unroll
    for (int m = 0; m < 8; ++m) {
        const int j = t + 32*m;
        const float4 uv = *(const float4*)(&U[j*SCP + s*4]);
        float w0d[7];
#pragma unroll
        for (int d = 0; d < 7; ++d) w0d[d] = W0[j*7 + d];
#pragma unroll
        for (int d = 0; d < 4; ++d) part[d] = fmaf(uv.x, w0d[d], part[d]);
#pragma unroll
        for (int d = 0; d < 7; ++d) {
            part[4  + d] = fmaf(uv.y, w0d[d], part[4  + d]);
            part[11 + d] = fmaf(uv.z, w0d[d], part[11 + d]);
            part[18 + d] = fmaf(uv.w, w0d[d], part[18 + d]);
        }
    }
#pragma unroll
    for (int off = 16; off >= 1; off >>= 1)
#pragma unroll
        for (int qq = 0; qq < 25; ++qq)
            part[qq] += __shfl_xor(part[qq], off, 64);
    if (t == 0) {
        const float* xs = x + (size_t)(samp0 + s)*7;
        const double x1 = xs[2], x2 = xs[3];
        const double dq0 = xs[4], dq1 = xs[5], dth = xs[6];
        double A[3][4];
#pragma unroll
        for (int i = 0; i < 3; ++i) {
            const double J0 = part[4 + i*7 + 0];
            const double J1 = part[4 + i*7 + 1];
            const double J2 = -x2*(double)part[4 + i*7 + 2] + x1*(double)part[4 + i*7 + 3];
            const double dL = (i == 0) ? (double)part[0]
                            : (i == 1) ? (double)part[1]
                            : (-x2*(double)part[2] + x1*(double)part[3]);
            A[i][0] = (double)part[4 + i*7 + 4] + (i == 0 ? EPS_REG : 0.0);
            A[i][1] = (double)part[4 + i*7 + 5] + (i == 1 ? EPS_REG : 0.0);
            A[i][2] = (double)part[4 + i*7 + 6] + (i == 2 ? EPS_REG : 0.0);
            A[i][3] = dL - (J0*dq0 + J1*dq1 + J2*dth);
        }
        for (int cc = 0; cc < 2; ++cc) {
            int piv = cc;
            double mx = fabs(A[cc][cc]);
            for (int rr = cc + 1; rr < 3; ++rr) {
                const double v = fabs(A[rr][cc]);
                if (v > mx) { mx = v; piv = rr; }
            }
            if (piv != cc) {
                for (int k2 = 0; k2 < 4; ++k2) {
                    const double tmp = A[cc][k2]; A[cc][k2] = A[piv][k2]; A[piv][k2] = tmp;
                }
            }
            const double inv = 1.0 / A[cc][cc];
            for (int rr = cc + 1; rr < 3; ++rr) {
                const double f = A[rr][cc] * inv;
                for (int k2 = cc + 1; k2 < 4; ++k2) A[rr][k2] -= f * A[cc][k2];
            }
        }
        const double sol2 = A[2][3] / A[2][2];
        const double sol1 = (A[1][3] - A[1][2]*sol2) / A[1][1];
        const double sol0 = (A[0][3] - A[0][1]*sol1 - A[0][2]*sol2) / A[0][0];
        float* o = out + (size_t)(samp0 + s)*7;
        o[0] = (float)dq0;
        o[1] = (float)dq1;
        o[2] = (float)(-x2*dth);
        o[3] = (float)( x1*dth);
        o[4] = (float)sol0;
        o[5] = (float)sol1;
        o[6] = (float)sol2;
    }
}

extern "C" void kernel_launch(void* const* d_in, const int* in_sizes, int n_in,
                              void* d_out, int out_size, void* d_ws, size_t ws_size,
                              hipStream_t stream) {
    const float* x  = (const float*)d_in[0];
    const float* W0 = (const float*)d_in[1];
    const float* b0 = (const float*)d_in[2];
    const float* W1 = (const float*)d_in[3];
    const float* b1 = (const float*)d_in[4];
    const float* W2 = (const float*)d_in[5];
    float* out = (float*)d_out;

    const int B = in_sizes[0] / 7;
    const size_t NEED = 6u * 65536u * sizeof(short);   // 768 KB of W1 fragments

    // One-time: allow >64KB dynamic LDS for the pipelined kernel (not a
    // stream op; safe under graph capture).
    static const bool big_lds_ok = [] {
        return hipFuncSetAttribute(reinterpret_cast<const void*>(lnn_pipe),
                                   hipFuncAttributeMaxDynamicSharedMemorySize,
                                   PIPE_LDS_BYTES) == hipSuccess;
    }();

    if (ws_size >= NEED && (B % 16) == 0 && big_lds_ok) {
        short* ws = (short*)d_ws;
        prep_w1_frags<<<128, 128, 0, stream>>>(W1, ws);
        lnn_pipe<<<B / 16, 1024, PIPE_LDS_BYTES, stream>>>(x, W0, b0, b1, W2, ws, out);
    } else if (ws_size >= NEED && (B % 8) == 0) {
        short* ws = (short*)d_ws;
        prep_w1_frags<<<128, 128, 0, stream>>>(W1, ws);
        lnn_mfma<<<B / 8, 512, 0, stream>>>(x, W0, b0, b1, W2, ws, out);
    } else {
        const int useT = (ws_size >= (size_t)HID * HID * sizeof(float)) ? 1 : 0;
        float* W1T = (float*)d_ws;
        if (useT) transpose_w1<<<64, 256, 0, stream>>>(W1, W1T);
        lnn_fused<<<B / TS8, 256, 0, stream>>>(x, W0, b0, W1, b1, W2, W1T, useT, out);
    }
}

// Round 4
// 291.848 us; speedup vs baseline: 1.0473x; 1.0473x over previous
//
#include <hip/hip_runtime.h>
#include <math.h>

#define HID 256
#define EPS_REG 1e-6

typedef __attribute__((ext_vector_type(8))) short short8;
typedef __attribute__((ext_vector_type(4))) short short4v;
typedef __attribute__((ext_vector_type(4))) float v4f;

#define MFMA_BF16(a, b, c) __builtin_amdgcn_mfma_f32_16x16x32_bf16((a), (b), (c), 0, 0, 0)

// ---------------------------------------------------------------------------
// Fast tanh: tanh(z) = 1 - 2/(exp(2z)+1). ~6 instr, <=2 ulp.
// ---------------------------------------------------------------------------
__device__ __forceinline__ float fast_tanh(float z) {
    const float e = __expf(2.0f * z);
    const float d = e + 1.0f;
    float r = __builtin_amdgcn_rcpf(d);
    r = r * (2.0f - d * r);              // Newton refine to full fp32
    return fmaf(-2.0f, r, 1.0f);
}

// ---------------------------------------------------------------------------
// Cheap RTN bf16 3-way split: v ~= hi + mid + lo (round-half-up, 2 ops/stage).
// ---------------------------------------------------------------------------
__device__ __forceinline__ float rtn_bf16(float v, short* s) {
    unsigned r = (__float_as_uint(v) + 0x8000u) & 0xFFFF0000u;
    *s = (short)(r >> 16);
    return __uint_as_float(r);
}
__device__ __forceinline__ void split3(float v, short* a, short* b, short* c) {
    float f0 = rtn_bf16(v, a);
    float r1 = v - f0;
    float f1 = rtn_bf16(r1, b);
    float r2 = r1 - f1;
    (void)rtn_bf16(r2, c);
}

// ---------------------------------------------------------------------------
// Prep: split W1 into bf16 hi/mid/lo laid out as per-lane MFMA A-fragments
// for phase 1 (A = W1 rows) and phase 2 (A = W1 columns). 6 x 128KB = 768KB.
// ---------------------------------------------------------------------------
__global__ void prep_w1_frags(const float* __restrict__ W1, short* __restrict__ ws) {
    const int gid   = blockIdx.x * 128 + threadIdx.x;   // 0..16383
    const int lane  = gid & 63;
    const int ks    = (gid >> 6) & 7;
    const int rt    = (gid >> 9) & 15;
    const int which = gid >> 13;                        // 0: A1, 1: A2
    const int m = lane & 15, q = lane >> 4;

    float v[8];
    if (which == 0) {
        const float* p = W1 + (size_t)(rt*16 + m)*HID + ks*32 + q*8;
        const float4 va = *(const float4*)(p);
        const float4 vb = *(const float4*)(p + 4);
        v[0]=va.x; v[1]=va.y; v[2]=va.z; v[3]=va.w;
        v[4]=vb.x; v[5]=vb.y; v[6]=vb.z; v[7]=vb.w;
    } else {
        const float* p = W1 + (size_t)(ks*32 + q*8)*HID + rt*16 + m;
#pragma unroll
        for (int t = 0; t < 8; ++t) v[t] = p[(size_t)t*HID];
    }
    short8 h8, m8, l8;
#pragma unroll
    for (int t = 0; t < 8; ++t) {
        short sh, sm, sl;
        split3(v[t], &sh, &sm, &sl);
        h8[t] = sh; m8[t] = sm; l8[t] = sl;
    }
    const size_t base = (size_t)which*3*65536 + ((size_t)(rt*8 + ks)*64 + lane)*8;
    *(short8*)(ws + base)          = h8;
    *(short8*)(ws + base + 65536)  = m8;
    *(short8*)(ws + base + 131072) = l8;
}

// ---------------------------------------------------------------------------
// R17: decoupled two-group pipeline with per-group LDS barriers + MM token.
// R13 recount: VALU-in-MM is negligible; ~96us of VALU sits in serial phases,
// and R13's 2 blocks/CU stay PHASE-LOCKED (same launch time, same cadence) so
// pipes never overlap (sum-of-pipes elapsed). R16's __syncthreads spanned all
// 16 waves -> forced lockstep + stretched MM (2 waves/SIMD vs L2 latency).
// Fix: NO cross-group barriers. Each 8-wave group runs the exact R13 chain
// with its OWN counting barrier (buffers disjoint); a bounded-wait token
// alternates MM phases between groups (A.MM1->B.MM1->A.MM2->B.MM2) so one
// group's MFMA always coincides with the other group's VALU phases. Token is
// pacing only -- correctness rests solely on per-group barriers (mirrors
// R13's syncthreads 1:1). Numerics bit-identical per group.
// ---------------------------------------------------------------------------
#define FRAG_NT_STRIDE 13056   // 3 bufs * 32 groups * 136 shorts
#define FRAG_BUF_STRIDE 4352   // 32 groups * 136
#define BFRAG_SHORTS 26112     // 2 nt * 13056
#define M0H_FLOATS 2304        // 256 * 9
#define PIPE_LDS_BYTES 122912  // 2*52224 + 2*9216 + 32 (sync)

// ---- per-group counting barrier on LDS (8 waves) --------------------------
__device__ __forceinline__ void gbar(int* ctr, int target) {
    __threadfence_block();     // drain this wave's LDS writes
    if ((threadIdx.x & 63) == 0)
        __hip_atomic_fetch_add(ctr, 1, __ATOMIC_ACQ_REL, __HIP_MEMORY_SCOPE_WORKGROUP);
    while (__hip_atomic_load(ctr, __ATOMIC_ACQUIRE, __HIP_MEMORY_SCOPE_WORKGROUP) < target)
        __builtin_amdgcn_s_sleep(1);
}
// ---- MM token: bounded wait (pacing only; timeout is safe) ----------------
__device__ __forceinline__ void tok_wait(int* tok, int g) {
    for (int i = 0; i < 8192; ++i) {
        if (__hip_atomic_load(tok, __ATOMIC_ACQUIRE, __HIP_MEMORY_SCOPE_WORKGROUP) == g)
            return;
        __builtin_amdgcn_s_sleep(2);
    }
}
__device__ __forceinline__ void tok_set(int* tok, int v) {
    __hip_atomic_store(tok, v, __ATOMIC_RELEASE, __HIP_MEMORY_SCOPE_WORKGROUP);
}

// ---- Phase 0: layer-0 forward + tangents --> M0 + B1 frags ----------------
__device__ __forceinline__ void lnn_phase0(const float* __restrict__ x,
    const float* __restrict__ W0, const float* __restrict__ b0,
    int samp_base, short* __restrict__ Bf, float* __restrict__ M0, int tid)
{
    const int j  = tid & 255;
    const int s0 = (tid >> 8) * 4;
    float w0r[7];
#pragma unroll
    for (int d = 0; d < 7; ++d) w0r[d] = W0[j*7 + d];
    const float bj = b0[j];
    const int kbase = (j >> 3)*136 + (j & 7);    // G*136 + t
#pragma unroll
    for (int si = 0; si < 4; ++si) {
        const int s = s0 + si;
        const float* xs = x + (size_t)(samp_base + s)*7;
        float z = bj;
#pragma unroll
        for (int d = 0; d < 7; ++d) z = fmaf(w0r[d], xs[d], z);
        const float h  = fast_tanh(z);
        const float sg = 1.0f - h*h;
        M0[j*9 + s] = h;
        const int nt = s >> 2;
        const int cb = (s & 3) * 4;              // col base within tile
        float vals[4] = {h, sg*w0r[4], sg*w0r[5], sg*w0r[6]};
#pragma unroll
        for (int comp = 0; comp < 4; ++comp) {
            short sh, sm, sl;
            split3(vals[comp], &sh, &sm, &sl);
            const int a = nt*FRAG_NT_STRIDE + kbase + (cb + comp)*8;
            Bf[a]                     = sh;
            Bf[a + FRAG_BUF_STRIDE]   = sm;
            Bf[a + 2*FRAG_BUF_STRIDE] = sl;
        }
    }
}

// ---- MFMA k-loop: acc += A x B (bf16x3, 6-product fp32 emulation) ---------
__device__ __forceinline__ void lnn_mm(const short8* __restrict__ Ah,
    const short8* __restrict__ Am, const short8* __restrict__ Al,
    const short* __restrict__ Bf, int w, int lane, int boff, v4f acc[2][2])
{
    short8 pah[2][2], pam[2][2], pal[2][2];   // [parity][rtl] A prefetch
#pragma unroll
    for (int rtl = 0; rtl < 2; ++rtl) {
        const size_t fi = ((size_t)((w*2 + rtl)*8))*64 + lane;
        pah[0][rtl] = Ah[fi]; pam[0][rtl] = Am[fi]; pal[0][rtl] = Al[fi];
    }
#pragma unroll
    for (int ks = 0; ks < 8; ++ks) {
        const int cur = ks & 1, nxt = cur ^ 1;
        if (ks < 7) {
#pragma unroll
            for (int rtl = 0; rtl < 2; ++rtl) {
                const size_t fi = ((size_t)((w*2 + rtl)*8 + ks + 1))*64 + lane;
                pah[nxt][rtl] = Ah[fi]; pam[nxt][rtl] = Am[fi]; pal[nxt][rtl] = Al[fi];
            }
        }
        short8 bh[2], bm[2], bl[2];
#pragma unroll
        for (int nt = 0; nt < 2; ++nt) {
            const int a = nt*FRAG_NT_STRIDE + ks*544 + boff;
            bh[nt] = *(const short8*)(&Bf[a]);
            bm[nt] = *(const short8*)(&Bf[a + FRAG_BUF_STRIDE]);
            bl[nt] = *(const short8*)(&Bf[a + 2*FRAG_BUF_STRIDE]);
        }
#pragma unroll
        for (int rtl = 0; rtl < 2; ++rtl) {
            const short8 ah = pah[cur][rtl];
            const short8 am = pam[cur][rtl];
            const short8 al = pal[cur][rtl];
#pragma unroll
            for (int nt = 0; nt < 2; ++nt) {
                acc[rtl][nt] = MFMA_BF16(ah, bl[nt], acc[rtl][nt]);
                acc[rtl][nt] = MFMA_BF16(al, bh[nt], acc[rtl][nt]);
                acc[rtl][nt] = MFMA_BF16(am, bm[nt], acc[rtl][nt]);
                acc[rtl][nt] = MFMA_BF16(am, bh[nt], acc[rtl][nt]);
                acc[rtl][nt] = MFMA_BF16(ah, bm[nt], acc[rtl][nt]);
                acc[rtl][nt] = MFMA_BF16(ah, bh[nt], acc[rtl][nt]);
            }
        }
    }
}

// ---- Epilogue 1: layer-2 nonlinearity + reverse seed --> B2 frags ---------
__device__ __forceinline__ void lnn_epi1(v4f acc[2][2], short* __restrict__ Bf,
    const float* __restrict__ b1, const float* __restrict__ W2,
    int w, int lane, int q, int c)
{
    const int myreg = c & 3;
#pragma unroll
    for (int rtl = 0; rtl < 2; ++rtl) {
        const int base = (w*2 + rtl)*16;
        float b1r[4], w2r[4];
#pragma unroll
        for (int r = 0; r < 4; ++r) {
            b1r[r] = b1[base + q*4 + r];
            w2r[r] = W2[base + q*4 + r];
        }
        const int G  = (base >> 3) + (q >> 1);
        const int tq = (q & 1) * 4;
#pragma unroll
        for (int nt = 0; nt < 2; ++nt) {
            short4v ph, pm, pl;
#pragma unroll
            for (int r = 0; r < 4; ++r) {
                const float z0 = __shfl(acc[rtl][nt][r] + b1r[r], lane & ~3, 64);
                const float h1 = fast_tanh(z0);
                const float s1 = 1.0f - h1*h1;
                const float av = acc[rtl][nt][r];
                const float u  = (myreg == 0) ? (w2r[r]*s1)
                                              : (-2.0f*w2r[r]*h1*s1)*av;
                short sh, sm, sl;
                split3(u, &sh, &sm, &sl);
                ph[r] = sh; pm[r] = sm; pl[r] = sl;
            }
            const int a = nt*FRAG_NT_STRIDE + G*136 + c*8 + tq;
            *(short4v*)(&Bf[a])                     = ph;
            *(short4v*)(&Bf[a + FRAG_BUF_STRIDE])   = pm;
            *(short4v*)(&Bf[a + 2*FRAG_BUF_STRIDE]) = pl;
        }
    }
}

// ---- Epilogue 2: back through layer-0 --> U0 plain (overlay Bf) -----------
__device__ __forceinline__ void lnn_epi2(v4f acc2[2][2], short* __restrict__ Bf,
    const float* __restrict__ M0, const float* __restrict__ W0,
    int w, int lane, int q, int c)
{
    float* U0 = (float*)Bf;      // [j][s*4+comp], stride 36
#pragma unroll
    for (int rtl = 0; rtl < 2; ++rtl) {
#pragma unroll
        for (int reg = 0; reg < 4; ++reg) {
            const int j = (w*2 + rtl)*16 + q*4 + reg;
            const float w0sel = W0[j*7 + 3 + (c & 3)];  // dummy read for comp 0
#pragma unroll
            for (int nt = 0; nt < 2; ++nt) {
                const int s = nt*4 + (c >> 2);
                const float pv = acc2[rtl][nt][reg];
                const float p0 = __shfl(pv, lane & ~3, 64);
                const float h0 = M0[j*9 + s];
                const float sg = 1.0f - h0*h0;
                const float t2 = -2.0f * p0 * h0 * sg;
                const float res = ((c & 3) == 0) ? (p0*sg)
                                                 : fmaf(pv, sg, t2 * w0sel);
                U0[j*36 + s*4 + (c & 3)] = res;
            }
        }
    }
}

// ---- Phase 3: project through W0^T, reduce, assemble, solve ---------------
__device__ __forceinline__ void lnn_phase3(const float* __restrict__ x,
    const float* __restrict__ W0, short* __restrict__ Bf,
    int samp_base, float* __restrict__ out, int w, int tid)
{
    const float* U0 = (const float*)Bf;
    float* scratch = ((float*)Bf) + 9216 + w * 425;   // [25][17]
    const int t = tid & 63;
    float part[25];
#pragma unroll
    for (int qq = 0; qq < 25; ++qq) part[qq] = 0.0f;

#pragma unroll
    for (int m = 0; m < 4; ++m) {
        const int j = t + 64*m;
        const float4 uv = *(const float4*)(&U0[j*36 + w*4]);
        float w0d[7];
#pragma unroll
        for (int d = 0; d < 7; ++d) w0d[d] = W0[j*7 + d];
#pragma unroll
        for (int d = 0; d < 4; ++d) part[d] = fmaf(uv.x, w0d[d], part[d]);
#pragma unroll
        for (int d = 0; d < 7; ++d) {
            part[4  + d] = fmaf(uv.y, w0d[d], part[4  + d]);
            part[11 + d] = fmaf(uv.z, w0d[d], part[11 + d]);
            part[18 + d] = fmaf(uv.w, w0d[d], part[18 + d]);
        }
    }
    // stages 1-2: quad-local sums
#pragma unroll
    for (int off = 1; off <= 2; off <<= 1)
#pragma unroll
        for (int qq = 0; qq < 25; ++qq)
            part[qq] += __shfl_xor(part[qq], off, 64);
    {
        const int quad = t >> 2;
        if ((t & 3) == 0) {
#pragma unroll
            for (int e = 0; e < 25; ++e)
                scratch[e*17 + quad] = part[e];
        }
    }
    if (t < 25) {
        float tot = 0.0f;
#pragma unroll
        for (int k = 0; k < 16; ++k) tot += scratch[t*17 + k];
        scratch[t*17 + 16] = tot;
    }

    if (t == 0) {
        double g[25];
#pragma unroll
        for (int e = 0; e < 25; ++e) g[e] = (double)scratch[e*17 + 16];

        const float* xs = x + (size_t)(samp_base + w)*7;
        const double x1 = xs[2], x2 = xs[3];
        const double dq0 = xs[4], dq1 = xs[5], dth = xs[6];

        double M[3][3], rhs[3];
#pragma unroll
        for (int i = 0; i < 3; ++i) {
            const double J0 = g[4 + i*7 + 0];
            const double J1 = g[4 + i*7 + 1];
            const double J2 = -x2*g[4 + i*7 + 2] + x1*g[4 + i*7 + 3];
            const double dL = (i == 0) ? g[0]
                            : (i == 1) ? g[1]
                            : (-x2*g[2] + x1*g[3]);
            M[i][0] = g[4 + i*7 + 4] + (i == 0 ? EPS_REG : 0.0);
            M[i][1] = g[4 + i*7 + 5] + (i == 1 ? EPS_REG : 0.0);
            M[i][2] = g[4 + i*7 + 6] + (i == 2 ? EPS_REG : 0.0);
            rhs[i]  = dL - (J0*dq0 + J1*dq1 + J2*dth);
        }
        // branch-free fp64 Cramer / adjugate solve
        const double c00 = M[1][1]*M[2][2] - M[1][2]*M[2][1];
        const double c01 = M[1][2]*M[2][0] - M[1][0]*M[2][2];
        const double c02 = M[1][0]*M[2][1] - M[1][1]*M[2][0];
        const double det = M[0][0]*c00 + M[0][1]*c01 + M[0][2]*c02;
        const double inv = 1.0 / det;
        const double c10 = M[0][2]*M[2][1] - M[0][1]*M[2][2];
        const double c11 = M[0][0]*M[2][2] - M[0][2]*M[2][0];
        const double c12 = M[0][1]*M[2][0] - M[0][0]*M[2][1];
        const double c20 = M[0][1]*M[1][2] - M[0][2]*M[1][1];
        const double c21 = M[0][2]*M[1][0] - M[0][0]*M[1][2];
        const double c22 = M[0][0]*M[1][1] - M[0][1]*M[1][0];
        const double sol0 = (c00*rhs[0] + c10*rhs[1] + c20*rhs[2]) * inv;
        const double sol1 = (c01*rhs[0] + c11*rhs[1] + c21*rhs[2]) * inv;
        const double sol2 = (c02*rhs[0] + c12*rhs[1] + c22*rhs[2]) * inv;

        float* o = out + (size_t)(samp_base + w)*7;
        o[0] = (float)dq0;
        o[1] = (float)dq1;
        o[2] = (float)(-x2*dth);
        o[3] = (float)( x1*dth);
        o[4] = (float)sol0;
        o[5] = (float)sol1;
        o[6] = (float)sol2;
    }
}

// ---------------------------------------------------------------------------
// Decoupled pipeline kernel: 1024 threads = group A (waves 0-7) + group B
// (waves 8-15). Each group runs the full R13 chain on its own samples and
// LDS half, synced by ITS OWN 8-wave counting barrier. The MM token
// serializes matrix phases A.MM1 -> B.MM1 -> A.MM2 -> B.MM2 so each group's
// MFMA overlaps the other's VALU phases via HW wave co-issue. One
// __syncthreads only, to publish zeroed sync vars.
// ---------------------------------------------------------------------------
__global__ __launch_bounds__(1024, 1)
void lnn_pipe2(const float* __restrict__ x,
               const float* __restrict__ W0, const float* __restrict__ b0,
               const float* __restrict__ b1, const float* __restrict__ W2,
               const short* __restrict__ ws,
               float* __restrict__ out)
{
    extern __shared__ __align__(16) short smem[];
    short* BfA = smem;                                // 26112 shorts
    short* BfB = smem + BFRAG_SHORTS;                 // 26112 shorts
    float* M0A = (float*)(smem + 2*BFRAG_SHORTS);     // 2304 floats
    float* M0B = M0A + M0H_FLOATS;                    // 2304 floats
    int*   syn = (int*)(M0B + M0H_FLOATS);            // [0]=arrA [1]=arrB [2]=tok

    const int tid  = threadIdx.x;
    if (tid < 3) syn[tid] = 0;
    __syncthreads();                                  // publish init (only full barrier)

    const int w16  = tid >> 6;
    const int g    = (w16 >= 8) ? 1 : 0;
    const int w    = w16 & 7;
    const int lane = tid & 63;
    const int gtid = w*64 + lane;

    short* Bf = g ? BfB : BfA;
    float* M0 = g ? M0B : M0A;
    int* arr  = &syn[g];
    int* tok  = &syn[2];
    const int samp0 = blockIdx.x * 16 + g*8;

    const short8* A1h = (const short8*)ws;
    const short8* A1m = A1h + 8192;
    const short8* A1l = A1h + 16384;
    const short8* A2h = A1h + 24576;
    const short8* A2m = A1h + 32768;
    const short8* A2l = A1h + 40960;

    const int q = lane >> 4;
    const int c = lane & 15;
    const int boff = q*136 + c*8;

    // ---- P0 (both groups concurrently; disjoint buffers) ----
    lnn_phase0(x, W0, b0, samp0, Bf, M0, gtid);
    gbar(arr, 8*1);

    // ---- MM1 (token: A first, then B while A runs E1) ----
    v4f acc[2][2];
#pragma unroll
    for (int r = 0; r < 2; ++r)
#pragma unroll
        for (int n = 0; n < 2; ++n) acc[r][n] = (v4f){0.f, 0.f, 0.f, 0.f};
    tok_wait(tok, g);
    lnn_mm(A1h, A1m, A1l, Bf, w, lane, boff, acc);
    gbar(arr, 8*2);
    if (gtid == 0) tok_set(tok, g ^ 1);

    // ---- E1 (VALU; overlaps other group's MM1) ----
    lnn_epi1(acc, Bf, b1, W2, w, lane, q, c);
    gbar(arr, 8*3);

    // ---- MM2 ----
    v4f acc2[2][2];
#pragma unroll
    for (int r = 0; r < 2; ++r)
#pragma unroll
        for (int n = 0; n < 2; ++n) acc2[r][n] = (v4f){0.f, 0.f, 0.f, 0.f};
    tok_wait(tok, g);
    lnn_mm(A2h, A2m, A2l, Bf, w, lane, boff, acc2);
    gbar(arr, 8*4);
    if (gtid == 0) tok_set(tok, g ^ 1);

    // ---- E2 + P3 (VALU; overlaps other group's MM2) ----
    lnn_epi2(acc2, Bf, M0, W0, w, lane, q, c);
    gbar(arr, 8*5);
    lnn_phase3(x, W0, Bf, samp0, out, w, gtid);
}

// ===========================================================================
// R13 8-sample kernel, kept as fallback (if >64KB dynamic LDS is refused or
// B % 16 != 0). Measured 226 us, MfmaUtil 42 / VALUBusy 43.
// ===========================================================================
__global__ __launch_bounds__(512, 4)
void lnn_mfma(const float* __restrict__ x,
              const float* __restrict__ W0, const float* __restrict__ b0,
              const float* __restrict__ b1, const float* __restrict__ W2,
              const short* __restrict__ ws,
              float* __restrict__ out)
{
    __shared__ __align__(16) short Bfrag[26112];     // 52224 B
    __shared__ float M0h[HID * 9];                   // h0 per (j, s), stride 9

    const int tid   = threadIdx.x;
    const int samp0 = blockIdx.x * 8;
    const int lane  = tid & 63;
    const int w     = tid >> 6;                      // wave 0..7

    lnn_phase0(x, W0, b0, samp0, Bfrag, M0h, tid);
    __syncthreads();

    const short8* A1h = (const short8*)ws;
    const short8* A1m = A1h + 8192;
    const short8* A1l = A1h + 16384;
    const short8* A2h = A1h + 24576;
    const short8* A2m = A1h + 32768;
    const short8* A2l = A1h + 40960;

    const int q = lane >> 4;
    const int c = lane & 15;
    const int boff = q*136 + c*8;

    v4f acc[2][2];
#pragma unroll
    for (int r = 0; r < 2; ++r)
#pragma unroll
        for (int n = 0; n < 2; ++n) acc[r][n] = (v4f){0.f, 0.f, 0.f, 0.f};
    lnn_mm(A1h, A1m, A1l, Bfrag, w, lane, boff, acc);
    __syncthreads();

    lnn_epi1(acc, Bfrag, b1, W2, w, lane, q, c);
    __syncthreads();

    v4f acc2[2][2];
#pragma unroll
    for (int r = 0; r < 2; ++r)
#pragma unroll
        for (int n = 0; n < 2; ++n) acc2[r][n] = (v4f){0.f, 0.f, 0.f, 0.f};
    lnn_mm(A2h, A2m, A2l, Bfrag, w, lane, boff, acc2);
    __syncthreads();

    lnn_epi2(acc2, Bfrag, M0h, W0, w, lane, q, c);
    __syncthreads();

    lnn_phase3(x, W0, Bfrag, samp0, out, w, tid);
}

// ===========================================================================
// Deep fallback (proven round-3 kernel, fp32 VALU): used if ws too small.
// ===========================================================================
#define TS8 8
#define SCP 36

__global__ void transpose_w1(const float* __restrict__ W1, float* __restrict__ W1T) {
    __shared__ float tile[32][33];
    const int bx = blockIdx.x & 7;
    const int by = blockIdx.x >> 3;
    const int tx = threadIdx.x & 31;
    const int ty = threadIdx.x >> 5;
#pragma unroll
    for (int q = 0; q < 4; ++q)
        tile[ty + q*8][tx] = W1[(by*32 + ty + q*8)*HID + bx*32 + tx];
    __syncthreads();
#pragma unroll
    for (int q = 0; q < 4; ++q)
        W1T[(bx*32 + ty + q*8)*HID + by*32 + tx] = tile[tx][ty + q*8];
}

__global__ __launch_bounds__(256, 2)
void lnn_fused(const float* __restrict__ x,
               const float* __restrict__ W0, const float* __restrict__ b0,
               const float* __restrict__ W1, const float* __restrict__ b1,
               const float* __restrict__ W2,
               const float* __restrict__ W1T, const int useT,
               float* __restrict__ out)
{
    __shared__ float M0[HID * SCP];
    __shared__ float U [HID * SCP];
    const int tid   = threadIdx.x;
    const int samp0 = blockIdx.x * TS8;
    {
        const int j = tid;
        float w0r[7];
#pragma unroll
        for (int d = 0; d < 7; ++d) w0r[d] = W0[j*7 + d];
        const float bj = b0[j];
#pragma unroll
        for (int s = 0; s < TS8; ++s) {
            const float* xs = x + (size_t)(samp0 + s)*7;
            float z = bj;
#pragma unroll
            for (int d = 0; d < 7; ++d) z = fmaf(w0r[d], xs[d], z);
            const float h  = tanhf(z);
            const float sg = 1.0f - h*h;
            float4 v = {h, sg * w0r[4], sg * w0r[5], sg * w0r[6]};
            *(float4*)(&M0[j*SCP + s*4]) = v;
        }
    }
    __syncthreads();
    const int it = tid & 63;
    const int ct = tid >> 6;
    float acc[4][8];
#pragma unroll
    for (int r = 0; r < 4; ++r)
#pragma unroll
        for (int c = 0; c < 8; ++c) acc[r][c] = 0.0f;
    if (useT) {
#pragma unroll 4
        for (int j = 0; j < HID; ++j) {
            const float4 w4 = *(const float4*)(W1T + (size_t)j*HID + it*4);
            const float4 ma = *(const float4*)(&M0[j*SCP + ct*8]);
            const float4 mb = *(const float4*)(&M0[j*SCP + ct*8 + 4]);
            const float w[4] = {w4.x, w4.y, w4.z, w4.w};
            const float m[8] = {ma.x, ma.y, ma.z, ma.w, mb.x, mb.y, mb.z, mb.w};
#pragma unroll
            for (int r = 0; r < 4; ++r)
#pragma unroll
                for (int c = 0; c < 8; ++c)
                    acc[r][c] = fmaf(w[r], m[c], acc[r][c]);
        }
    } else {
#pragma unroll 2
        for (int j = 0; j < HID; ++j) {
            float w[4];
#pragma unroll
            for (int r = 0; r < 4; ++r) w[r] = W1[(size_t)(it*4 + r)*HID + j];
            const float4 ma = *(const float4*)(&M0[j*SCP + ct*8]);
            const float4 mb = *(const float4*)(&M0[j*SCP + ct*8 + 4]);
            const float m[8] = {ma.x, ma.y, ma.z, ma.w, mb.x, mb.y, mb.z, mb.w};
#pragma unroll
            for (int r = 0; r < 4; ++r)
#pragma unroll
                for (int c = 0; c < 8; ++c)
                    acc[r][c] = fmaf(w[r], m[c], acc[r][c]);
        }
    }
    {
#pragma unroll
        for (int r = 0; r < 4; ++r) {
            const int i = it*4 + r;
            const float b1i = b1[i];
            const float w2i = W2[i];
#pragma unroll
            for (int cs = 0; cs < 2; ++cs) {
                const float z1 = acc[r][cs*4+0] + b1i;
                const float h1 = tanhf(z1);
                const float s1 = 1.0f - h1*h1;
                float4 uv;
                uv.x = w2i * s1;
                const float m2 = -2.0f * w2i * h1 * s1;
                uv.y = m2 * acc[r][cs*4+1];
                uv.z = m2 * acc[r][cs*4+2];
                uv.w = m2 * acc[r][cs*4+3];
                *(float4*)(&U[i*SCP + ct*8 + cs*4]) = uv;
            }
        }
    }
    __syncthreads();
    float acc2[4][8];
#pragma unroll
    for (int r = 0; r < 4; ++r)
#pragma unroll
        for (int c = 0; c < 8; ++c) acc2[r][c] = 0.0f;
#pragma unroll 4
    for (int i = 0; i < HID; ++i) {
        const float4 w4 = *(const float4*)(W1 + (size_t)i*HID + it*4);
        const float4 ua = *(const float4*)(&U[i*SCP + ct*8]);
        const float4 ub = *(const float4*)(&U[i*SCP + ct*8 + 4]);
        const float w[4] = {w4.x, w4.y, w4.z, w4.w};
        const float m[8] = {ua.x, ua.y, ua.z, ua.w, ub.x, ub.y, ub.z, ub.w};
#pragma unroll
        for (int r = 0; r < 4; ++r)
#pragma unroll
            for (int c = 0; c < 8; ++c)
                acc2[r][c] = fmaf(w[r], m[c], acc2[r][c]);
    }
    __syncthreads();
    {
#pragma unroll
        for (int r = 0; r < 4; ++r) {
            const int j = it*4 + r;
#pragma unroll
            for (int cs = 0; cs < 2; ++cs) {
                const int scb = ct*8 + cs*4;
                const float4 mm = *(const float4*)(&M0[j*SCP + scb]);
                const float h0v = mm.x;
                const float sg  = 1.0f - h0v*h0v;
                const float p   = acc2[r][cs*4+0];
                const float t2  = -2.0f * p * h0v;
                float4 uv;
                uv.x = p * sg;
                uv.y = fmaf(acc2[r][cs*4+1], sg, t2 * mm.y);
                uv.z = fmaf(acc2[r][cs*4+2], sg, t2 * mm.z);
                uv.w = fmaf(acc2[r][cs*4+3], sg, t2 * mm.w);
                *(float4*)(&U[j*SCP + scb]) = uv;
            }
        }
    }
    __syncthreads();
    const int s = tid >> 5;
    const int t = tid & 31;
    float part[25];
#pragma unroll
    for (int qq = 0; qq < 25; ++qq) part[qq] = 0.0f;
#pragma unroll
    for (int m = 0; m < 8; ++m) {
        const int j = t + 32*m;
        const float4 uv = *(const float4*)(&U[j*SCP + s*4]);
        float w0d[7];
#pragma unroll
        for (int d = 0; d < 7; ++d) w0d[d] = W0[j*7 + d];
#pragma unroll
        for (int d = 0; d < 4; ++d) part[d] = fmaf(uv.x, w0d[d], part[d]);
#pragma unroll
        for (int d = 0; d < 7; ++d) {
            part[4  + d] = fmaf(uv.y, w0d[d], part[4  + d]);
            part[11 + d] = fmaf(uv.z, w0d[d], part[11 + d]);
            part[18 + d] = fmaf(uv.w, w0d[d], part[18 + d]);
        }
    }
#pragma unroll
    for (int off = 16; off >= 1; off >>= 1)
#pragma unroll
        for (int qq = 0; qq < 25; ++qq)
            part[qq] += __shfl_xor(part[qq], off, 64);
    if (t == 0) {
        const float* xs = x + (size_t)(samp0 + s)*7;
        const double x1 = xs[2], x2 = xs[3];
        const double dq0 = xs[4], dq1 = xs[5], dth = xs[6];
        double A[3][4];
#pragma unroll
        for (int i = 0; i < 3; ++i) {
            const double J0 = part[4 + i*7 + 0];
            const double J1 = part[4 + i*7 + 1];
            const double J2 = -x2*(double)part[4 + i*7 + 2] + x1*(double)part[4 + i*7 + 3];
            const double dL = (i == 0) ? (double)part[0]
                            : (i == 1) ? (double)part[1]
                            : (-x2*(double)part[2] + x1*(double)part[3]);
            A[i][0] = (double)part[4 + i*7 + 4] + (i == 0 ? EPS_REG : 0.0);
            A[i][1] = (double)part[4 + i*7 + 5] + (i == 1 ? EPS_REG : 0.0);
            A[i][2] = (double)part[4 + i*7 + 6] + (i == 2 ? EPS_REG : 0.0);
            A[i][3] = dL - (J0*dq0 + J1*dq1 + J2*dth);
        }
        for (int cc = 0; cc < 2; ++cc) {
            int piv = cc;
            double mx = fabs(A[cc][cc]);
            for (int rr = cc + 1; rr < 3; ++rr) {
                const double v = fabs(A[rr][cc]);
                if (v > mx) { mx = v; piv = rr; }
            }
            if (piv != cc) {
                for (int k2 = 0; k2 < 4; ++k2) {
                    const double tmp = A[cc][k2]; A[cc][k2] = A[piv][k2]; A[piv][k2] = tmp;
                }
            }
            const double inv = 1.0 / A[cc][cc];
            for (int rr = cc + 1; rr < 3; ++rr) {
                const double f = A[rr][cc] * inv;
                for (int k2 = cc + 1; k2 < 4; ++k2) A[rr][k2] -= f * A[cc][k2];
            }
        }
        const double sol2 = A[2][3] / A[2][2];
        const double sol1 = (A[1][3] - A[1][2]*sol2) / A[1][1];
        const double sol0 = (A[0][3] - A[0][1]*sol1 - A[0][2]*sol2) / A[0][0];
        float* o = out + (size_t)(samp0 + s)*7;
        o[0] = (float)dq0;
        o[1] = (float)dq1;
        o[2] = (float)(-x2*dth);
        o[3] = (float)( x1*dth);
        o[4] = (float)sol0;
        o[5] = (float)sol1;
        o[6] = (float)sol2;
    }
}

extern "C" void kernel_launch(void* const* d_in, const int* in_sizes, int n_in,
                              void* d_out, int out_size, void* d_ws, size_t ws_size,
                              hipStream_t stream) {
    const float* x  = (const float*)d_in[0];
    const float* W0 = (const float*)d_in[1];
    const float* b0 = (const float*)d_in[2];
    const float* W1 = (const float*)d_in[3];
    const float* b1 = (const float*)d_in[4];
    const float* W2 = (const float*)d_in[5];
    float* out = (float*)d_out;

    const int B = in_sizes[0] / 7;
    const size_t NEED = 6u * 65536u * sizeof(short);   // 768 KB of W1 fragments

    // One-time: allow >64KB dynamic LDS for the pipelined kernel (not a
    // stream op; safe under graph capture).
    static const bool big_lds_ok = [] {
        return hipFuncSetAttribute(reinterpret_cast<const void*>(lnn_pipe2),
                                   hipFuncAttributeMaxDynamicSharedMemorySize,
                                   PIPE_LDS_BYTES) == hipSuccess;
    }();

    if (ws_size >= NEED && (B % 16) == 0 && big_lds_ok) {
        short* ws = (short*)d_ws;
        prep_w1_frags<<<128, 128, 0, stream>>>(W1, ws);
        lnn_pipe2<<<B / 16, 1024, PIPE_LDS_BYTES, stream>>>(x, W0, b0, b1, W2, ws, out);
    } else if (ws_size >= NEED && (B % 8) == 0) {
        short* ws = (short*)d_ws;
        prep_w1_frags<<<128, 128, 0, stream>>>(W1, ws);
        lnn_mfma<<<B / 8, 512, 0, stream>>>(x, W0, b0, b1, W2, ws, out);
    } else {
        const int useT = (ws_size >= (size_t)HID * HID * sizeof(float)) ? 1 : 0;
        float* W1T = (float*)d_ws;
        if (useT) transpose_w1<<<64, 256, 0, stream>>>(W1, W1T);
        lnn_fused<<<B / TS8, 256, 0, stream>>>(x, W0, b0, W1, b1, W2, W1T, useT, out);
    }
}

// Round 6
// 276.048 us; speedup vs baseline: 1.1072x; 1.0572x over previous
//
#include <hip/hip_runtime.h>
#include <math.h>

#define HID 256
#define EPS_REG 1e-6

typedef __attribute__((ext_vector_type(8))) short short8;
typedef __attribute__((ext_vector_type(4))) short short4v;
typedef __attribute__((ext_vector_type(4))) float v4f;

#define MFMA_BF16(a, b, c) __builtin_amdgcn_mfma_f32_16x16x32_bf16((a), (b), (c), 0, 0, 0)

// ---------------------------------------------------------------------------
// Fast tanh: tanh(z) = 1 - 2/(exp(2z)+1). ~6 instr, <=2 ulp.
// ---------------------------------------------------------------------------
__device__ __forceinline__ float fast_tanh(float z) {
    const float e = __expf(2.0f * z);
    const float d = e + 1.0f;
    float r = __builtin_amdgcn_rcpf(d);
    r = r * (2.0f - d * r);              // Newton refine to full fp32
    return fmaf(-2.0f, r, 1.0f);
}

// ---------------------------------------------------------------------------
// Cheap RTN bf16 3-way split: v ~= hi + mid + lo (round-half-up, 2 ops/stage).
// R18 lesson: 2-way split (err ~2^-17) FAILS the 1402 absmax budget (11520).
// 6-product bf16x3 (err ~2^-26) is the proven floor; do not cheapen.
// ---------------------------------------------------------------------------
__device__ __forceinline__ float rtn_bf16(float v, short* s) {
    unsigned r = (__float_as_uint(v) + 0x8000u) & 0xFFFF0000u;
    *s = (short)(r >> 16);
    return __uint_as_float(r);
}
__device__ __forceinline__ void split3(float v, short* a, short* b, short* c) {
    float f0 = rtn_bf16(v, a);
    float r1 = v - f0;
    float f1 = rtn_bf16(r1, b);
    float r2 = r1 - f1;
    (void)rtn_bf16(r2, c);
}

// ---------------------------------------------------------------------------
// Prep: split W1 into bf16 hi/mid/lo laid out as per-lane MFMA A-fragments
// for phase 1 (A = W1 rows) and phase 2 (A = W1 columns). 6 x 128KB = 768KB.
// ---------------------------------------------------------------------------
__global__ void prep_w1_frags(const float* __restrict__ W1, short* __restrict__ ws) {
    const int gid   = blockIdx.x * 128 + threadIdx.x;   // 0..16383
    const int lane  = gid & 63;
    const int ks    = (gid >> 6) & 7;
    const int rt    = (gid >> 9) & 15;
    const int which = gid >> 13;                        // 0: A1, 1: A2
    const int m = lane & 15, q = lane >> 4;

    float v[8];
    if (which == 0) {
        const float* p = W1 + (size_t)(rt*16 + m)*HID + ks*32 + q*8;
        const float4 va = *(const float4*)(p);
        const float4 vb = *(const float4*)(p + 4);
        v[0]=va.x; v[1]=va.y; v[2]=va.z; v[3]=va.w;
        v[4]=vb.x; v[5]=vb.y; v[6]=vb.z; v[7]=vb.w;
    } else {
        const float* p = W1 + (size_t)(ks*32 + q*8)*HID + rt*16 + m;
#pragma unroll
        for (int t = 0; t < 8; ++t) v[t] = p[(size_t)t*HID];
    }
    short8 h8, m8, l8;
#pragma unroll
    for (int t = 0; t < 8; ++t) {
        short sh, sm, sl;
        split3(v[t], &sh, &sm, &sl);
        h8[t] = sh; m8[t] = sm; l8[t] = sl;
    }
    const size_t base = (size_t)which*3*65536 + ((size_t)(rt*8 + ks)*64 + lane)*8;
    *(short8*)(ws + base)          = h8;
    *(short8*)(ws + base + 65536)  = m8;
    *(short8*)(ws + base + 131072) = l8;
}

// ---------------------------------------------------------------------------
// R19: revert to the proven R13 6-product kernel (absmax 768 / 1402 budget)
// and apply three BIT-IDENTICAL micro-optimizations:
//  1. P0 remap thread->(4 consecutive j, 1 sample): 48 ds_write_b16 ->
//     12 ds_write_b64, x-loads 28->7, W0 as 7 coalesced float4.
//  2. E1 quad tanh dedup: 4 lanes computed the same 16 tanh; now gather z
//     (4 shfl + 3 sel), 1 tanh/lane/item-group, redistribute h1,s1 (8 shfl).
//  3. MM product-major MFMA order: 4 independent accumulator chains between
//     dependent MFMA pairs (per-acc product order unchanged).
// ---------------------------------------------------------------------------
#define FRAG_NT_STRIDE 13056   // 3 bufs * 32 groups * 136 shorts
#define FRAG_BUF_STRIDE 4352   // 32 groups * 136

// ---- Phase 0: layer-0 forward + tangents --> M0 + B1 frags ----------------
// thread -> (j0 = 4*(tid&63) .. j0+3, s = tid>>6); vectorized b64 frag stores.
__device__ __forceinline__ void lnn_phase0(const float* __restrict__ x,
    const float* __restrict__ W0, const float* __restrict__ b0,
    int samp_base, short* __restrict__ Bf, float* __restrict__ M0, int tid)
{
    const int jq = tid & 63;
    const int s  = tid >> 6;
    const int j0 = jq * 4;
    const float* xs = x + (size_t)(samp_base + s)*7;
    float xv[7];
#pragma unroll
    for (int d = 0; d < 7; ++d) xv[d] = xs[d];
    float4 wv[7];
    const float* wp = W0 + (size_t)j0*7;     // 28 floats, 16B-aligned (28*4*jq)
#pragma unroll
    for (int k = 0; k < 7; ++k) wv[k] = *(const float4*)(wp + 4*k);
    const float* wf = (const float*)wv;      // wf[jj*7 + d]
    const int nt = s >> 2;
    const int cb = (s & 3) * 4;
    const int G  = j0 >> 3;
    const int t0 = j0 & 7;                   // 0 or 4
    short4v hi4[4], mi4[4], lo4[4];          // [comp][jj]
#pragma unroll
    for (int jj = 0; jj < 4; ++jj) {
        const int j = j0 + jj;
        float z = b0[j];
#pragma unroll
        for (int d = 0; d < 7; ++d) z = fmaf(wf[jj*7 + d], xv[d], z);
        const float h  = fast_tanh(z);
        const float sg = 1.0f - h*h;
        M0[j*9 + s] = h;
        float vals[4] = {h, sg*wf[jj*7 + 4], sg*wf[jj*7 + 5], sg*wf[jj*7 + 6]};
#pragma unroll
        for (int comp = 0; comp < 4; ++comp) {
            short sh, sm, sl;
            split3(vals[comp], &sh, &sm, &sl);
            hi4[comp][jj] = sh; mi4[comp][jj] = sm; lo4[comp][jj] = sl;
        }
    }
#pragma unroll
    for (int comp = 0; comp < 4; ++comp) {
        const int a = nt*FRAG_NT_STRIDE + G*136 + t0 + (cb + comp)*8;
        *(short4v*)(&Bf[a])                     = hi4[comp];
        *(short4v*)(&Bf[a + FRAG_BUF_STRIDE])   = mi4[comp];
        *(short4v*)(&Bf[a + 2*FRAG_BUF_STRIDE]) = lo4[comp];
    }
}

// ---- MFMA k-loop: acc += A x B (bf16x3, 6-product), product-major order ---
__device__ __forceinline__ void lnn_mm(const short8* __restrict__ Ah,
    const short8* __restrict__ Am, const short8* __restrict__ Al,
    const short* __restrict__ Bf, int w, int lane, int boff, v4f acc[2][2])
{
    short8 pah[2][2], pam[2][2], pal[2][2];   // [parity][rtl] A prefetch
#pragma unroll
    for (int rtl = 0; rtl < 2; ++rtl) {
        const size_t fi = ((size_t)((w*2 + rtl)*8))*64 + lane;
        pah[0][rtl] = Ah[fi]; pam[0][rtl] = Am[fi]; pal[0][rtl] = Al[fi];
    }
#pragma unroll
    for (int ks = 0; ks < 8; ++ks) {
        const int cur = ks & 1, nxt = cur ^ 1;
        if (ks < 7) {
#pragma unroll
            for (int rtl = 0; rtl < 2; ++rtl) {
                const size_t fi = ((size_t)((w*2 + rtl)*8 + ks + 1))*64 + lane;
                pah[nxt][rtl] = Ah[fi]; pam[nxt][rtl] = Am[fi]; pal[nxt][rtl] = Al[fi];
            }
        }
        short8 bh[2], bm[2], bl[2];
#pragma unroll
        for (int nt = 0; nt < 2; ++nt) {
            const int a = nt*FRAG_NT_STRIDE + ks*544 + boff;
            bh[nt] = *(const short8*)(&Bf[a]);
            bm[nt] = *(const short8*)(&Bf[a + FRAG_BUF_STRIDE]);
            bl[nt] = *(const short8*)(&Bf[a + 2*FRAG_BUF_STRIDE]);
        }
        const short8 ah0 = pah[cur][0], ah1 = pah[cur][1];
        const short8 am0 = pam[cur][0], am1 = pam[cur][1];
        const short8 al0 = pal[cur][0], al1 = pal[cur][1];
        // product-major: 4 independent chains between dependent pairs;
        // per-accumulator order matches R13 exactly (bit-identical).
        acc[0][0] = MFMA_BF16(ah0, bl[0], acc[0][0]);
        acc[0][1] = MFMA_BF16(ah0, bl[1], acc[0][1]);
        acc[1][0] = MFMA_BF16(ah1, bl[0], acc[1][0]);
        acc[1][1] = MFMA_BF16(ah1, bl[1], acc[1][1]);

        acc[0][0] = MFMA_BF16(al0, bh[0], acc[0][0]);
        acc[0][1] = MFMA_BF16(al0, bh[1], acc[0][1]);
        acc[1][0] = MFMA_BF16(al1, bh[0], acc[1][0]);
        acc[1][1] = MFMA_BF16(al1, bh[1], acc[1][1]);

        acc[0][0] = MFMA_BF16(am0, bm[0], acc[0][0]);
        acc[0][1] = MFMA_BF16(am0, bm[1], acc[0][1]);
        acc[1][0] = MFMA_BF16(am1, bm[0], acc[1][0]);
        acc[1][1] = MFMA_BF16(am1, bm[1], acc[1][1]);

        acc[0][0] = MFMA_BF16(am0, bh[0], acc[0][0]);
        acc[0][1] = MFMA_BF16(am0, bh[1], acc[0][1]);
        acc[1][0] = MFMA_BF16(am1, bh[0], acc[1][0]);
        acc[1][1] = MFMA_BF16(am1, bh[1], acc[1][1]);

        acc[0][0] = MFMA_BF16(ah0, bm[0], acc[0][0]);
        acc[0][1] = MFMA_BF16(ah0, bm[1], acc[0][1]);
        acc[1][0] = MFMA_BF16(ah1, bm[0], acc[1][0]);
        acc[1][1] = MFMA_BF16(ah1, bm[1], acc[1][1]);

        acc[0][0] = MFMA_BF16(ah0, bh[0], acc[0][0]);
        acc[0][1] = MFMA_BF16(ah0, bh[1], acc[0][1]);
        acc[1][0] = MFMA_BF16(ah1, bh[0], acc[1][0]);
        acc[1][1] = MFMA_BF16(ah1, bh[1], acc[1][1]);
    }
}

// ---- Epilogue 1: layer-2 nonlinearity + reverse seed --> B2 frags ---------
// Quad tanh dedup: gather 4 z's, 1 tanh per lane, redistribute h1,s1.
// u expression order matches R13 exactly (bit-identical).
__device__ __forceinline__ void lnn_epi1(v4f acc[2][2], short* __restrict__ Bf,
    const float* __restrict__ b1, const float* __restrict__ W2,
    int w, int lane, int q, int c)
{
    const int myreg = c & 3;
    const int qbase = lane & ~3;
#pragma unroll
    for (int rtl = 0; rtl < 2; ++rtl) {
        const int base = (w*2 + rtl)*16;
        float b1r[4], w2r[4];
#pragma unroll
        for (int r = 0; r < 4; ++r) {
            b1r[r] = b1[base + q*4 + r];
            w2r[r] = W2[base + q*4 + r];
        }
        const int G  = (base >> 3) + (q >> 1);
        const int tq = (q & 1) * 4;
#pragma unroll
        for (int nt = 0; nt < 2; ++nt) {
            // gather the quad-base pre-activations for all 4 r
            const float zb0 = __shfl(acc[rtl][nt][0] + b1r[0], qbase, 64);
            const float zb1 = __shfl(acc[rtl][nt][1] + b1r[1], qbase, 64);
            const float zb2 = __shfl(acc[rtl][nt][2] + b1r[2], qbase, 64);
            const float zb3 = __shfl(acc[rtl][nt][3] + b1r[3], qbase, 64);
            // each lane evaluates tanh for r == myreg only
            const float zsel = (myreg == 0) ? zb0
                             : (myreg == 1) ? zb1
                             : (myreg == 2) ? zb2 : zb3;
            const float ht = fast_tanh(zsel);
            const float st = 1.0f - ht*ht;
            // redistribute h1, s1 across the quad
            float h1v[4], s1v[4];
#pragma unroll
            for (int r = 0; r < 4; ++r) {
                h1v[r] = __shfl(ht, qbase + r, 64);
                s1v[r] = __shfl(st, qbase + r, 64);
            }
            short4v ph, pm, pl;
#pragma unroll
            for (int r = 0; r < 4; ++r) {
                const float av = acc[rtl][nt][r];
                const float u  = (myreg == 0) ? (w2r[r]*s1v[r])
                                              : (-2.0f*w2r[r]*h1v[r]*s1v[r])*av;
                short sh, sm, sl;
                split3(u, &sh, &sm, &sl);
                ph[r] = sh; pm[r] = sm; pl[r] = sl;
            }
            const int a = nt*FRAG_NT_STRIDE + G*136 + c*8 + tq;
            *(short4v*)(&Bf[a])                     = ph;
            *(short4v*)(&Bf[a + FRAG_BUF_STRIDE])   = pm;
            *(short4v*)(&Bf[a + 2*FRAG_BUF_STRIDE]) = pl;
        }
    }
}

// ---- Epilogue 2: back through layer-0 --> U0 plain (overlay Bfrag) --------
__device__ __forceinline__ void lnn_epi2(v4f acc2[2][2], short* __restrict__ Bf,
    const float* __restrict__ M0, const float* __restrict__ W0,
    int w, int lane, int q, int c)
{
    float* U0 = (float*)Bf;      // [j][s*4+comp], stride 36
#pragma unroll
    for (int rtl = 0; rtl < 2; ++rtl) {
#pragma unroll
        for (int reg = 0; reg < 4; ++reg) {
            const int j = (w*2 + rtl)*16 + q*4 + reg;
            const float w0sel = W0[j*7 + 3 + (c & 3)];  // dummy read for comp 0
#pragma unroll
            for (int nt = 0; nt < 2; ++nt) {
                const int s = nt*4 + (c >> 2);
                const float pv = acc2[rtl][nt][reg];
                const float p0 = __shfl(pv, lane & ~3, 64);
                const float h0 = M0[j*9 + s];
                const float sg = 1.0f - h0*h0;
                const float t2 = -2.0f * p0 * h0 * sg;
                const float res = ((c & 3) == 0) ? (p0*sg)
                                                 : fmaf(pv, sg, t2 * w0sel);
                U0[j*36 + s*4 + (c & 3)] = res;
            }
        }
    }
}

// ---- Phase 3: project through W0^T, reduce, assemble, solve ---------------
__device__ __forceinline__ void lnn_phase3(const float* __restrict__ x,
    const float* __restrict__ W0, short* __restrict__ Bf,
    int samp_base, float* __restrict__ out, int w, int tid)
{
    const float* U0 = (const float*)Bf;
    float* scratch = ((float*)Bf) + 9216 + w * 425;   // [25][17]
    const int t = tid & 63;
    float part[25];
#pragma unroll
    for (int qq = 0; qq < 25; ++qq) part[qq] = 0.0f;

#pragma unroll
    for (int m = 0; m < 4; ++m) {
        const int j = t + 64*m;
        const float4 uv = *(const float4*)(&U0[j*36 + w*4]);
        float w0d[7];
#pragma unroll
        for (int d = 0; d < 7; ++d) w0d[d] = W0[j*7 + d];
#pragma unroll
        for (int d = 0; d < 4; ++d) part[d] = fmaf(uv.x, w0d[d], part[d]);
#pragma unroll
        for (int d = 0; d < 7; ++d) {
            part[4  + d] = fmaf(uv.y, w0d[d], part[4  + d]);
            part[11 + d] = fmaf(uv.z, w0d[d], part[11 + d]);
            part[18 + d] = fmaf(uv.w, w0d[d], part[18 + d]);
        }
    }
    // stages 1-2: quad-local sums
#pragma unroll
    for (int off = 1; off <= 2; off <<= 1)
#pragma unroll
        for (int qq = 0; qq < 25; ++qq)
            part[qq] += __shfl_xor(part[qq], off, 64);
    {
        const int quad = t >> 2;
        if ((t & 3) == 0) {
#pragma unroll
            for (int e = 0; e < 25; ++e)
                scratch[e*17 + quad] = part[e];
        }
    }
    if (t < 25) {
        float tot = 0.0f;
#pragma unroll
        for (int k = 0; k < 16; ++k) tot += scratch[t*17 + k];
        scratch[t*17 + 16] = tot;
    }

    if (t == 0) {
        double g[25];
#pragma unroll
        for (int e = 0; e < 25; ++e) g[e] = (double)scratch[e*17 + 16];

        const float* xs = x + (size_t)(samp_base + w)*7;
        const double x1 = xs[2], x2 = xs[3];
        const double dq0 = xs[4], dq1 = xs[5], dth = xs[6];

        double M[3][3], rhs[3];
#pragma unroll
        for (int i = 0; i < 3; ++i) {
            const double J0 = g[4 + i*7 + 0];
            const double J1 = g[4 + i*7 + 1];
            const double J2 = -x2*g[4 + i*7 + 2] + x1*g[4 + i*7 + 3];
            const double dL = (i == 0) ? g[0]
                            : (i == 1) ? g[1]
                            : (-x2*g[2] + x1*g[3]);
            M[i][0] = g[4 + i*7 + 4] + (i == 0 ? EPS_REG : 0.0);
            M[i][1] = g[4 + i*7 + 5] + (i == 1 ? EPS_REG : 0.0);
            M[i][2] = g[4 + i*7 + 6] + (i == 2 ? EPS_REG : 0.0);
            rhs[i]  = dL - (J0*dq0 + J1*dq1 + J2*dth);
        }
        // branch-free fp64 Cramer / adjugate solve
        const double c00 = M[1][1]*M[2][2] - M[1][2]*M[2][1];
        const double c01 = M[1][2]*M[2][0] - M[1][0]*M[2][2];
        const double c02 = M[1][0]*M[2][1] - M[1][1]*M[2][0];
        const double det = M[0][0]*c00 + M[0][1]*c01 + M[0][2]*c02;
        const double inv = 1.0 / det;
        const double c10 = M[0][2]*M[2][1] - M[0][1]*M[2][2];
        const double c11 = M[0][0]*M[2][2] - M[0][2]*M[2][0];
        const double c12 = M[0][1]*M[2][0] - M[0][0]*M[2][1];
        const double c20 = M[0][1]*M[1][2] - M[0][2]*M[1][1];
        const double c21 = M[0][2]*M[1][0] - M[0][0]*M[1][2];
        const double c22 = M[0][0]*M[1][1] - M[0][1]*M[1][0];
        const double sol0 = (c00*rhs[0] + c10*rhs[1] + c20*rhs[2]) * inv;
        const double sol1 = (c01*rhs[0] + c11*rhs[1] + c21*rhs[2]) * inv;
        const double sol2 = (c02*rhs[0] + c12*rhs[1] + c22*rhs[2]) * inv;

        float* o = out + (size_t)(samp_base + w)*7;
        o[0] = (float)dq0;
        o[1] = (float)dq1;
        o[2] = (float)(-x2*dth);
        o[3] = (float)( x1*dth);
        o[4] = (float)sol0;
        o[5] = (float)sol1;
        o[6] = (float)sol2;
    }
}

// ---------------------------------------------------------------------------
// Main kernel: R13 structure (8 samples/block, 512 thr, 2 blocks/CU).
// ---------------------------------------------------------------------------
__global__ __launch_bounds__(512, 4)
void lnn_mfma(const float* __restrict__ x,
              const float* __restrict__ W0, const float* __restrict__ b0,
              const float* __restrict__ b1, const float* __restrict__ W2,
              const short* __restrict__ ws,
              float* __restrict__ out)
{
    __shared__ __align__(16) short Bfrag[26112];     // 52224 B
    __shared__ float M0h[HID * 9];                   // h0 per (j, s), stride 9

    const int tid   = threadIdx.x;
    const int samp0 = blockIdx.x * 8;
    const int lane  = tid & 63;
    const int w     = tid >> 6;                      // wave 0..7

    lnn_phase0(x, W0, b0, samp0, Bfrag, M0h, tid);
    __syncthreads();

    const short8* A1h = (const short8*)ws;
    const short8* A1m = A1h + 8192;
    const short8* A1l = A1h + 16384;
    const short8* A2h = A1h + 24576;
    const short8* A2m = A1h + 32768;
    const short8* A2l = A1h + 40960;

    const int q = lane >> 4;
    const int c = lane & 15;
    const int boff = q*136 + c*8;

    v4f acc[2][2];
#pragma unroll
    for (int r = 0; r < 2; ++r)
#pragma unroll
        for (int n = 0; n < 2; ++n) acc[r][n] = (v4f){0.f, 0.f, 0.f, 0.f};
    lnn_mm(A1h, A1m, A1l, Bfrag, w, lane, boff, acc);
    __syncthreads();

    lnn_epi1(acc, Bfrag, b1, W2, w, lane, q, c);
    __syncthreads();

    v4f acc2[2][2];
#pragma unroll
    for (int r = 0; r < 2; ++r)
#pragma unroll
        for (int n = 0; n < 2; ++n) acc2[r][n] = (v4f){0.f, 0.f, 0.f, 0.f};
    lnn_mm(A2h, A2m, A2l, Bfrag, w, lane, boff, acc2);
    __syncthreads();

    lnn_epi2(acc2, Bfrag, M0h, W0, w, lane, q, c);
    __syncthreads();

    lnn_phase3(x, W0, Bfrag, samp0, out, w, tid);
}

// ===========================================================================
// Deep fallback (proven round-3 kernel, fp32 VALU): used if ws too small.
// ===========================================================================
#define TS8 8
#define SCP 36

__global__ void transpose_w1(const float* __restrict__ W1, float* __restrict__ W1T) {
    __shared__ float tile[32][33];
    const int bx = blockIdx.x & 7;
    const int by = blockIdx.x >> 3;
    const int tx = threadIdx.x & 31;
    const int ty = threadIdx.x >> 5;
#pragma unroll
    for (int q = 0; q < 4; ++q)
        tile[ty + q*8][tx] = W1[(by*32 + ty + q*8)*HID + bx*32 + tx];
    __syncthreads();
#pragma unroll
    for (int q = 0; q < 4; ++q)
        W1T[(bx*32 + ty + q*8)*HID + by*32 + tx] = tile[tx][ty + q*8];
}

__global__ __launch_bounds__(256, 2)
void lnn_fused(const float* __restrict__ x,
               const float* __restrict__ W0, const float* __restrict__ b0,
               const float* __restrict__ W1, const float* __restrict__ b1,
               const float* __restrict__ W2,
               const float* __restrict__ W1T, const int useT,
               float* __restrict__ out)
{
    __shared__ float M0[HID * SCP];
    __shared__ float U [HID * SCP];
    const int tid   = threadIdx.x;
    const int samp0 = blockIdx.x * TS8;
    {
        const int j = tid;
        float w0r[7];
#pragma unroll
        for (int d = 0; d < 7; ++d) w0r[d] = W0[j*7 + d];
        const float bj = b0[j];
#pragma unroll
        for (int s = 0; s < TS8; ++s) {
            const float* xs = x + (size_t)(samp0 + s)*7;
            float z = bj;
#pragma unroll
            for (int d = 0; d < 7; ++d) z = fmaf(w0r[d], xs[d], z);
            const float h  = tanhf(z);
            const float sg = 1.0f - h*h;
            float4 v = {h, sg * w0r[4], sg * w0r[5], sg * w0r[6]};
            *(float4*)(&M0[j*SCP + s*4]) = v;
        }
    }
    __syncthreads();
    const int it = tid & 63;
    const int ct = tid >> 6;
    float acc[4][8];
#pragma unroll
    for (int r = 0; r < 4; ++r)
#pragma unroll
        for (int c = 0; c < 8; ++c) acc[r][c] = 0.0f;
    if (useT) {
#pragma unroll 4
        for (int j = 0; j < HID; ++j) {
            const float4 w4 = *(const float4*)(W1T + (size_t)j*HID + it*4);
            const float4 ma = *(const float4*)(&M0[j*SCP + ct*8]);
            const float4 mb = *(const float4*)(&M0[j*SCP + ct*8 + 4]);
            const float w[4] = {w4.x, w4.y, w4.z, w4.w};
            const float m[8] = {ma.x, ma.y, ma.z, ma.w, mb.x, mb.y, mb.z, mb.w};
#pragma unroll
            for (int r = 0; r < 4; ++r)
#pragma unroll
                for (int c = 0; c < 8; ++c)
                    acc[r][c] = fmaf(w[r], m[c], acc[r][c]);
        }
    } else {
#pragma unroll 2
        for (int j = 0; j < HID; ++j) {
            float w[4];
#pragma unroll
            for (int r = 0; r < 4; ++r) w[r] = W1[(size_t)(it*4 + r)*HID + j];
            const float4 ma = *(const float4*)(&M0[j*SCP + ct*8]);
            const float4 mb = *(const float4*)(&M0[j*SCP + ct*8 + 4]);
            const float m[8] = {ma.x, ma.y, ma.z, ma.w, mb.x, mb.y, mb.z, mb.w};
#pragma unroll
            for (int r = 0; r < 4; ++r)
#pragma unroll
                for (int c = 0; c < 8; ++c)
                    acc[r][c] = fmaf(w[r], m[c], acc[r][c]);
        }
    }
    {
#pragma unroll
        for (int r = 0; r < 4; ++r) {
            const int i = it*4 + r;
            const float b1i = b1[i];
            const float w2i = W2[i];
#pragma unroll
            for (int cs = 0; cs < 2; ++cs) {
                const float z1 = acc[r][cs*4+0] + b1i;
                const float h1 = tanhf(z1);
                const float s1 = 1.0f - h1*h1;
                float4 uv;
                uv.x = w2i * s1;
                const float m2 = -2.0f * w2i * h1 * s1;
                uv.y = m2 * acc[r][cs*4+1];
                uv.z = m2 * acc[r][cs*4+2];
                uv.w = m2 * acc[r][cs*4+3];
                *(float4*)(&U[i*SCP + ct*8 + cs*4]) = uv;
            }
        }
    }
    __syncthreads();
    float acc2[4][8];
#pragma unroll
    for (int r = 0; r < 4; ++r)
#pragma unroll
        for (int c = 0; c < 8; ++c) acc2[r][c] = 0.0f;
#pragma unroll 4
    for (int i = 0; i < HID; ++i) {
        const float4 w4 = *(const float4*)(W1 + (size_t)i*HID + it*4);
        const float4 ua = *(const float4*)(&U[i*SCP + ct*8]);
        const float4 ub = *(const float4*)(&U[i*SCP + ct*8 + 4]);
        const float w[4] = {w4.x, w4.y, w4.z, w4.w};
        const float m[8] = {ua.x, ua.y, ua.z, ua.w, ub.x, ub.y, ub.z, ub.w};
#pragma unroll
        for (int r = 0; r < 4; ++r)
#pragma unroll
            for (int c = 0; c < 8; ++c)
                acc2[r][c] = fmaf(w[r], m[c], acc2[r][c]);
    }
    __syncthreads();
    {
#pragma unroll
        for (int r = 0; r < 4; ++r) {
            const int j = it*4 + r;
#pragma unroll
            for (int cs = 0; cs < 2; ++cs) {
                const int scb = ct*8 + cs*4;
                const float4 mm = *(const float4*)(&M0[j*SCP + scb]);
                const float h0v = mm.x;
                const float sg  = 1.0f - h0v*h0v;
                const float p   = acc2[r][cs*4+0];
                const float t2  = -2.0f * p * h0v;
                float4 uv;
                uv.x = p * sg;
                uv.y = fmaf(acc2[r][cs*4+1], sg, t2 * mm.y);
                uv.z = fmaf(acc2[r][cs*4+2], sg, t2 * mm.z);
                uv.w = fmaf(acc2[r][cs*4+3], sg, t2 * mm.w);
                *(float4*)(&U[j*SCP + scb]) = uv;
            }
        }
    }
    __syncthreads();
    const int s = tid >> 5;
    const int t = tid & 31;
    float part[25];
#pragma unroll
    for (int qq = 0; qq < 25; ++qq) part[qq] = 0.0f;
#pragma unroll
    for (int m = 0; m < 8; ++m) {
        const int j = t + 32*m;
        const float4 uv = *(const float4*)(&U[j*SCP + s*4]);
        float w0d[7];
#pragma unroll
        for (int d = 0; d < 7; ++d) w0d[d] = W0[j*7 + d];
#pragma unroll
        for (int d = 0; d < 4; ++d) part[d] = fmaf(uv.x, w0d[d], part[d]);
#pragma unroll
        for (int d = 0; d < 7; ++d) {
            part[4  + d] = fmaf(uv.y, w0d[d], part[4  + d]);
            part[11 + d] = fmaf(uv.z, w0d[d], part[11 + d]);
            part[18 + d] = fmaf(uv.w, w0d[d], part[18 + d]);
        }
    }
#pragma unroll
    for (int off = 16; off >= 1; off >>= 1)
#pragma unroll
        for (int qq = 0; qq < 25; ++qq)
            part[qq] += __shfl_xor(part[qq], off, 64);
    if (t == 0) {
        const float* xs = x + (size_t)(samp0 + s)*7;
        const double x1 = xs[2], x2 = xs[3];
        const double dq0 = xs[4], dq1 = xs[5], dth = xs[6];
        double A[3][4];
#pragma unroll
        for (int i = 0; i < 3; ++i) {
            const double J0 = part[4 + i*7 + 0];
            const double J1 = part[4 + i*7 + 1];
            const double J2 = -x2*(double)part[4 + i*7 + 2] + x1*(double)part[4 + i*7 + 3];
            const double dL = (i == 0) ? (double)part[0]
                            : (i == 1) ? (double)part[1]
                            : (-x2*(double)part[2] + x1*(double)part[3]);
            A[i][0] = (double)part[4 + i*7 + 4] + (i == 0 ? EPS_REG : 0.0);
            A[i][1] = (double)part[4 + i*7 + 5] + (i == 1 ? EPS_REG : 0.0);
            A[i][2] = (double)part[4 + i*7 + 6] + (i == 2 ? EPS_REG : 0.0);
            A[i][3] = dL - (J0*dq0 + J1*dq1 + J2*dth);
        }
        for (int cc = 0; cc < 2; ++cc) {
            int piv = cc;
            double mx = fabs(A[cc][cc]);
            for (int rr = cc + 1; rr < 3; ++rr) {
                const double v = fabs(A[rr][cc]);
                if (v > mx) { mx = v; piv = rr; }
            }
            if (piv != cc) {
                for (int k2 = 0; k2 < 4; ++k2) {
                    const double tmp = A[cc][k2]; A[cc][k2] = A[piv][k2]; A[piv][k2] = tmp;
                }
            }
            const double inv = 1.0 / A[cc][cc];
            for (int rr = cc + 1; rr < 3; ++rr) {
                const double f = A[rr][cc] * inv;
                for (int k2 = cc + 1; k2 < 4; ++k2) A[rr][k2] -= f * A[cc][k2];
            }
        }
        const double sol2 = A[2][3] / A[2][2];
        const double sol1 = (A[1][3] - A[1][2]*sol2) / A[1][1];
        const double sol0 = (A[0][3] - A[0][1]*sol1 - A[0][2]*sol2) / A[0][0];
        float* o = out + (size_t)(samp0 + s)*7;
        o[0] = (float)dq0;
        o[1] = (float)dq1;
        o[2] = (float)(-x2*dth);
        o[3] = (float)( x1*dth);
        o[4] = (float)sol0;
        o[5] = (float)sol1;
        o[6] = (float)sol2;
    }
}

extern "C" void kernel_launch(void* const* d_in, const int* in_sizes, int n_in,
                              void* d_out, int out_size, void* d_ws, size_t ws_size,
                              hipStream_t stream) {
    const float* x  = (const float*)d_in[0];
    const float* W0 = (const float*)d_in[1];
    const float* b0 = (const float*)d_in[2];
    const float* W1 = (const float*)d_in[3];
    const float* b1 = (const float*)d_in[4];
    const float* W2 = (const float*)d_in[5];
    float* out = (float*)d_out;

    const int B = in_sizes[0] / 7;
    const size_t NEED = 6u * 65536u * sizeof(short);   // 768 KB of W1 fragments

    if (ws_size >= NEED && (B % 8) == 0) {
        short* ws = (short*)d_ws;
        prep_w1_frags<<<128, 128, 0, stream>>>(W1, ws);
        lnn_mfma<<<B / 8, 512, 0, stream>>>(x, W0, b0, b1, W2, ws, out);
    } else {
        const int useT = (ws_size >= (size_t)HID * HID * sizeof(float)) ? 1 : 0;
        float* W1T = (float*)d_ws;
        if (useT) transpose_w1<<<64, 256, 0, stream>>>(W1, W1T);
        lnn_fused<<<B / TS8, 256, 0, stream>>>(x, W0, b0, W1, b1, W2, W1T, useT, out);
    }
}